// Round 13
// baseline (126.489 us; speedup 1.0000x reference)
//
#include <hip/hip_runtime.h>
#include <math.h>

#define BB   8
#define NN   4096
#define KK   10
#define TPB  256
#define NPTS (BB * NN)      // 32768

// KNN: 16 lanes per group, 4 points per group (point-batched broadcast reads)
#define GPP  16
#define PPG  4
#define NGRP (TPB / GPP)            // 16 groups
#define PPB  (NGRP * PPG)           // 64 points per block
#define BPBK (NN / PPB)             // 64 blocks per batch
#define KNBLK (BB * BPBK)           // 512 blocks
#define TILE 512
#define CAP  48

// SVD-side: 256 blocks, each covers 128 points x {cloud1, cloud2}
#define SVDBLK 256
#define SBLK   256

// --- LAPACK environment constants (reference = numpy float32 sgesdd) ---
#define LARTG_OLD 0
#define EPSV  5.9604644775390625e-8    // 2^-24
#define UNFLV 1.1754943508222875e-38   // 2^-126
#define TOLV (10.0 * EPSV)

static __device__ __forceinline__ double lapy2d(double x, double y) {
  double xa = fabs(x), ya = fabs(y);
  double w = fmax(xa, ya), z = fmin(xa, ya);
  if (z == 0.0) return w;
  double q = z / w;
  return w * sqrt(1.0 + q * q);
}

static __device__ __forceinline__ void lartg(double f, double g,
                                             double &c, double &s, double &r) {
#if LARTG_OLD
  if (g == 0.0) { c = 1.0; s = 0.0; r = f; }
  else if (f == 0.0) { c = 0.0; s = 1.0; r = g; }
  else {
    double d = sqrt(f * f + g * g);
    c = f / d; s = g / d; r = d;
    if (fabs(f) > fabs(g) && c < 0.0) { c = -c; s = -s; r = -r; }
  }
#else
  if (g == 0.0) { c = 1.0; s = 0.0; r = f; }
  else if (f == 0.0) { c = 0.0; s = copysign(1.0, g); r = fabs(g); }
  else {
    double d = sqrt(f * f + g * g);
    c = fabs(f) / d;
    r = copysign(d, f);
    s = g / r;
  }
#endif
}

static __device__ void las2(double f, double g, double h, double &ssmin, double &ssmax) {
  double fa = fabs(f), ga = fabs(g), ha = fabs(h);
  double fhmn = fmin(fa, ha), fhmx = fmax(fa, ha);
  if (fhmn == 0.0) {
    ssmin = 0.0;
    if (fhmx == 0.0) ssmax = ga;
    else {
      double mn = fmin(fhmx, ga), mx = fmax(fhmx, ga);
      double rr = mn / mx;
      ssmax = mx * sqrt(1.0 + rr * rr);
    }
  } else {
    if (ga < fhmx) {
      double as_ = 1.0 + fhmn / fhmx;
      double at  = (fhmx - fhmn) / fhmx;
      double au  = (ga / fhmx); au = au * au;
      double c   = 2.0 / (sqrt(as_ * as_ + au) + sqrt(at * at + au));
      ssmin = fhmn * c;
      ssmax = fhmx / c;
    } else {
      double au = fhmx / ga;
      if (au == 0.0) { ssmin = (fhmn * fhmx) / ga; ssmax = ga; }
      else {
        double as_ = 1.0 + fhmn / fhmx;
        double at  = (fhmx - fhmn) / fhmx;
        double t1 = as_ * au, t2 = at * au;
        double c = 1.0 / (sqrt(1.0 + t1 * t1) + sqrt(1.0 + t2 * t2));
        ssmin = (fhmn * c) * au; ssmin = ssmin + ssmin;
        ssmax = ga / (c + c);
      }
    }
  }
}

static __device__ void lasv2(double f, double g, double h,
                             double &ssmin, double &ssmax,
                             double &snr, double &csr, double &snl, double &csl) {
  double ft = f, fa = fabs(f), ht = h, ha = fabs(h);
  int pmax = 1;
  bool swp = (ha > fa);
  if (swp) { pmax = 3; double t = ft; ft = ht; ht = t; t = fa; fa = ha; ha = t; }
  double gt = g, ga = fabs(g);
  double clt = 0, crt = 0, slt = 0, srt = 0;
  if (ga == 0.0) {
    ssmin = ha; ssmax = fa;
    clt = 1.0; crt = 1.0; slt = 0.0; srt = 0.0;
  } else {
    bool gasmal = true;
    if (ga > fa) {
      pmax = 2;
      if ((fa / ga) < EPSV) {
        gasmal = false;
        ssmax = ga;
        if (ha > 1.0) ssmin = fa / (ga / ha);
        else          ssmin = (fa / ga) * ha;
        clt = 1.0; slt = ht / gt; srt = 1.0; crt = ft / gt;
      }
    }
    if (gasmal) {
      double dd = fa - ha, l;
      if (dd == fa) l = 1.0; else l = dd / fa;
      double mv = gt / ft;
      double t = 2.0 - l;
      double mm = mv * mv, tt = t * t;
      double s = sqrt(tt + mm);
      double r = (l == 0.0) ? fabs(mv) : sqrt(l * l + mm);
      double a = 0.5 * (s + r);
      ssmin = ha / a;
      ssmax = fa * a;
      if (mm == 0.0) {
        if (l == 0.0) t = copysign(2.0, ft) * copysign(1.0, gt);
        else          t = gt / copysign(dd, ft) + mv / t;
      } else {
        t = (mv / (s + t) + mv / (r + l)) * (1.0 + a);
      }
      double lq = sqrt(t * t + 4.0);
      crt = 2.0 / lq;
      srt = t / lq;
      clt = (crt + srt * mv) / a;
      slt = (ht / ft) * srt / a;
    }
  }
  if (swp) { csl = srt; snl = crt; csr = slt; snr = clt; }
  else     { csl = clt; snl = slt; csr = crt; snr = srt; }
  double tsign = 1.0;
  if (pmax == 1) tsign = copysign(1.0, csr) * copysign(1.0, csl) * copysign(1.0, f);
  if (pmax == 2) tsign = copysign(1.0, snr) * copysign(1.0, csl) * copysign(1.0, g);
  if (pmax == 3) tsign = copysign(1.0, snr) * copysign(1.0, snl) * copysign(1.0, h);
  ssmax = copysign(ssmax, tsign);
  ssmin = copysign(ssmin, tsign * copysign(1.0, f) * copysign(1.0, h));
}

static __device__ __forceinline__ void rot_rows(double vt[3][3], int lo, double c, double s) {
  if (c != 1.0 || s != 0.0) {
    for (int k = 0; k < 3; ++k) {
      double tp = vt[lo + 1][k];
      vt[lo + 1][k] = c * tp - s * vt[lo][k];
      vt[lo][k]     = s * tp + c * vt[lo][k];
    }
  }
}

static __device__ void bdsqr3(double d[3], double e[2], double vt[3][3]) {
  const double tol = TOLV;
  double sminoa = fabs(d[0]);
  if (sminoa != 0.0) {
    double mu = sminoa;
    mu = fabs(d[1]) * (mu / (mu + fabs(e[0])));
    sminoa = fmin(sminoa, mu);
    if (sminoa != 0.0) {
      mu = fabs(d[2]) * (mu / (mu + fabs(e[1])));
      sminoa = fmin(sminoa, mu);
    }
  }
  sminoa /= sqrt(3.0);
  double thresh = fmax(tol * sminoa, 54.0 * UNFLV);
  int m = 3, oldll = -1, oldm = -1, idir = 0;
  double sminl = 0.0;
  for (int guard = 0; guard < 500 && m > 1; ++guard) {
    double smax = fabs(d[m - 1]);
    int ll = 0;
    bool split = false;
    for (int lll = 1; lll <= m - 1; ++lll) {
      int l = m - lll;
      double abss = fabs(d[l - 1]);
      double abse = fabs(e[l - 1]);
      if (abse <= thresh) { ll = l; split = true; break; }
      smax = fmax(smax, fmax(abss, abse));
    }
    if (split) {
      e[ll - 1] = 0.0;
      if (ll == m - 1) { m = m - 1; continue; }
      ll = ll + 1;
    } else ll = 1;
    if (ll == m - 1) {
      double sigmn, sigmx, sinr, cosr, sinl, cosl;
      lasv2(d[m - 2], e[m - 2], d[m - 1], sigmn, sigmx, sinr, cosr, sinl, cosl);
      d[m - 2] = sigmx; e[m - 2] = 0.0; d[m - 1] = sigmn;
      for (int k = 0; k < 3; ++k) {
        double x = vt[m - 2][k], y = vt[m - 1][k];
        vt[m - 2][k] = cosr * x + sinr * y;
        vt[m - 1][k] = cosr * y - sinr * x;
      }
      m -= 2;
      continue;
    }
    if (ll > oldm || m < oldll)
      idir = (fabs(d[ll - 1]) >= fabs(d[m - 1])) ? 1 : 2;
    bool deflated = false;
    if (idir == 1) {
      if (fabs(e[m - 2]) <= tol * fabs(d[m - 1])) { e[m - 2] = 0.0; continue; }
      double mu = fabs(d[ll - 1]);
      sminl = mu;
      for (int lll = ll; lll <= m - 1; ++lll) {
        if (fabs(e[lll - 1]) <= tol * mu) { e[lll - 1] = 0.0; deflated = true; break; }
        mu = fabs(d[lll]) * (mu / (mu + fabs(e[lll - 1])));
        sminl = fmin(sminl, mu);
      }
    } else {
      if (fabs(e[ll - 1]) <= tol * fabs(d[ll - 1])) { e[ll - 1] = 0.0; continue; }
      double mu = fabs(d[m - 1]);
      sminl = mu;
      for (int lll = m - 1; lll >= ll; --lll) {
        if (fabs(e[lll - 1]) <= tol * mu) { e[lll - 1] = 0.0; deflated = true; break; }
        mu = fabs(d[lll - 1]) * (mu / (mu + fabs(e[lll - 1])));
        sminl = fmin(sminl, mu);
      }
    }
    if (deflated) continue;
    oldll = ll; oldm = m;
    double shift = 0.0, rdum = 0.0;
    if (!(3.0 * tol * (sminl / smax) <= fmax(EPSV, 0.01 * tol))) {
      double sll;
      if (idir == 1) { sll = fabs(d[ll - 1]); las2(d[m - 2], e[m - 2], d[m - 1], shift, rdum); }
      else           { sll = fabs(d[m - 1]); las2(d[ll - 1], e[ll - 1], d[ll], shift, rdum); }
      if (sll > 0.0 && (shift / sll) * (shift / sll) < EPSV) shift = 0.0;
    }
    double csv[2], snv[2];
    if (shift == 0.0) {
      if (idir == 1) {
        double cs = 1.0, oldcs = 1.0, sn = 0.0, oldsn = 0.0, r = 0.0;
        for (int i = ll; i <= m - 1; ++i) {
          lartg(d[i - 1] * cs, e[i - 1], cs, sn, r);
          if (i > ll) e[i - 2] = oldsn * r;
          lartg(oldcs * r, d[i] * sn, oldcs, oldsn, d[i - 1]);
          csv[i - ll] = cs; snv[i - ll] = sn;
        }
        double h = d[m - 1] * cs;
        d[m - 1] = h * oldcs;
        e[m - 2] = h * oldsn;
        for (int j = 0; j <= m - ll - 1; ++j) rot_rows(vt, ll - 1 + j, csv[j], snv[j]);
        if (fabs(e[m - 2]) <= thresh) e[m - 2] = 0.0;
      } else {
        double cs = 1.0, oldcs = 1.0, sn = 0.0, oldsn = 0.0, r = 0.0;
        for (int i = m; i >= ll + 1; --i) {
          lartg(d[i - 1] * cs, e[i - 2], cs, sn, r);
          if (i < m) e[i - 1] = oldsn * r;
          lartg(oldcs * r, d[i - 2] * sn, oldcs, oldsn, d[i - 1]);
          csv[i - ll - 1] = oldcs; snv[i - ll - 1] = -oldsn;
        }
        double h = d[ll - 1] * cs;
        d[ll - 1] = h * oldcs;
        e[ll - 1] = h * oldsn;
        for (int j = m - ll - 1; j >= 0; --j) rot_rows(vt, ll - 1 + j, csv[j], snv[j]);
        if (fabs(e[ll - 1]) <= thresh) e[ll - 1] = 0.0;
      }
    } else {
      if (idir == 1) {
        double f = (fabs(d[ll - 1]) - shift) * (copysign(1.0, d[ll - 1]) + shift / d[ll - 1]);
        double g = e[ll - 1], cosr, sinr, cosl, sinl, r;
        for (int i = ll; i <= m - 1; ++i) {
          lartg(f, g, cosr, sinr, r);
          if (i > ll) e[i - 2] = r;
          f = cosr * d[i - 1] + sinr * e[i - 1];
          e[i - 1] = cosr * e[i - 1] - sinr * d[i - 1];
          g = sinr * d[i];
          d[i] = cosr * d[i];
          lartg(f, g, cosl, sinl, r);
          d[i - 1] = r;
          f = cosl * e[i - 1] + sinl * d[i];
          d[i] = cosl * d[i] - sinl * e[i - 1];
          if (i < m - 1) { g = sinl * e[i]; e[i] = cosl * e[i]; }
          csv[i - ll] = cosr; snv[i - ll] = sinr;
        }
        e[m - 2] = f;
        for (int j = 0; j <= m - ll - 1; ++j) rot_rows(vt, ll - 1 + j, csv[j], snv[j]);
        if (fabs(e[m - 2]) <= thresh) e[m - 2] = 0.0;
      } else {
        double f = (fabs(d[m - 1]) - shift) * (copysign(1.0, d[m - 1]) + shift / d[m - 1]);
        double g = e[m - 2], cosr, sinr, cosl, sinl, r;
        for (int i = m; i >= ll + 1; --i) {
          lartg(f, g, cosr, sinr, r);
          if (i < m) e[i - 1] = r;
          f = cosr * d[i - 1] + sinr * e[i - 2];
          e[i - 2] = cosr * e[i - 2] - sinr * d[i - 1];
          g = sinr * d[i - 2];
          d[i - 2] = cosr * d[i - 2];
          lartg(f, g, cosl, sinl, r);
          d[i - 1] = r;
          f = cosl * e[i - 2] + sinl * d[i - 2];
          d[i - 2] = cosl * d[i - 2] - sinl * e[i - 2];
          if (i > ll + 1) { g = sinl * e[i - 3]; e[i - 3] = cosl * e[i - 3]; }
          csv[i - ll - 1] = cosr; snv[i - ll - 1] = sinr;
        }
        e[ll - 1] = f;
        for (int j = m - ll - 1; j >= 0; --j) rot_rows(vt, ll - 1 + j, csv[j], snv[j]);
        if (fabs(e[ll - 1]) <= thresh) e[ll - 1] = 0.0;
      }
    }
  }
  for (int i = 0; i < 3; ++i)
    if (d[i] < 0.0) { d[i] = -d[i]; for (int k = 0; k < 3; ++k) vt[i][k] = -vt[i][k]; }
}

static __device__ void lapack_normal(double A[KK][3], double &nx, double &ny, double &nz) {
#pragma unroll
  for (int i = 0; i < 3; ++i) {
    double ss = 0.0;
#pragma unroll
    for (int j = i + 1; j < KK; ++j) ss += A[j][i] * A[j][i];
    double xnorm = sqrt(ss);
    if (xnorm != 0.0) {
      double alpha = A[i][i];
      double beta = -copysign(lapy2d(alpha, xnorm), alpha);
      double tau = (beta - alpha) / beta;
      double sc = 1.0 / (alpha - beta);
#pragma unroll
      for (int j = i + 1; j < KK; ++j) A[j][i] *= sc;
      A[i][i] = beta;
#pragma unroll
      for (int c = i + 1; c < 3; ++c) {
        double w = A[i][c];
#pragma unroll
        for (int j = i + 1; j < KK; ++j) w += A[j][i] * A[j][c];
        w *= tau;
        A[i][c] -= w;
#pragma unroll
        for (int j = i + 1; j < KK; ++j) A[j][c] -= w * A[j][i];
      }
    }
  }
  double r11 = A[0][0], r12 = A[0][1], r13 = A[0][2];
  double r22 = A[1][1], r23 = A[1][2], r33 = A[2][2];
  double d[3], e[2];
  double taup1 = 0.0, v3 = 0.0;
  d[0] = r11;
  double a22 = r22, a23 = r23, a32 = 0.0, a33 = r33;
  if (r13 != 0.0) {
    double betap = -copysign(lapy2d(r12, r13), r12);
    taup1 = (betap - r12) / betap;
    v3 = r13 / (r12 - betap);
    e[0] = betap;
    double w2 = (a22 + a23 * v3) * taup1;
    a22 -= w2; a23 -= w2 * v3;
    double w3 = (a33 * v3) * taup1;
    a32 = -w3; a33 -= w3 * v3;
  } else {
    e[0] = r12;
  }
  if (a32 != 0.0) {
    double beta2 = -copysign(lapy2d(a22, a32), a22);
    double tq = (beta2 - a22) / beta2;
    double v2 = a32 / (a22 - beta2);
    d[1] = beta2;
    double w = (a23 + v2 * a33) * tq;
    a23 -= w; a33 -= w * v2;
  } else d[1] = a22;
  e[1] = a23;
  d[2] = a33;
  double vt[3][3] = {{1,0,0},{0,1,0},{0,0,1}};
  bdsqr3(d, e, vt);
  int im = 0;
  if (d[1] < d[im]) im = 1;
  if (d[2] < d[im]) im = 2;
  double w1 = vt[im][0], w2 = vt[im][1], w3 = vt[im][2];
  double sdot = (w2 + w3 * v3) * taup1;
  w2 -= sdot; w3 -= sdot * v3;
  double inv = 1.0 / sqrt(w1 * w1 + w2 * w2 + w3 * w3);
  nx = w1 * inv; ny = w2 * inv; nz = w3 * inv;
}

// ---------------- Kernel 1: point-batched s-space probe-bound KNN ----------------
#define INS2(Kp) { bool lt_ = x < Kp; unsigned long long old_ = Kp; Kp = lt_ ? x : Kp; x = lt_ ? old_ : x; }
#define CSWAPU(U,V) { if (V < U) { unsigned long long t_ = U; U = V; V = t_; } }
#define CSWAPFD(U,V) { float mx_ = fmaxf(U, V); V = fminf(U, V); U = mx_; }   // descending

// pinned score: identical instruction sequence everywhere (qw = -0.5*|q|^2)
static __device__ __forceinline__ float score_s(float qx, float qy, float qz, float qw,
                                                float xi, float yi, float zi) {
  return fmaf(xi, qx, fmaf(yi, qy, fmaf(zi, qz, qw)));
}
static __device__ __forceinline__ float sqnorm(float x, float y, float z) {
  return __fadd_rn(__fadd_rn(__fmul_rn(x, x), __fmul_rn(y, y)), __fmul_rn(z, z));
}
// key: ascending-u64 order == (s descending, idx ascending) == top_k order
static __device__ __forceinline__ unsigned long long s_key(float s, int idx) {
  unsigned u = __float_as_uint(s);
  u = (u & 0x80000000u) ? ~u : (u | 0x80000000u);   // monotone increasing in s
  return ((unsigned long long)(~u) << 32) | (unsigned)idx;
}

__global__ __launch_bounds__(TPB, 1)
void lfl_knn(const float* __restrict__ xyz1, int* __restrict__ idxbuf) {
  __shared__ float4 tile[TILE];                       // 8 KB
  __shared__ unsigned long long gbuf[PPB][CAP];       // 24 KB
  __shared__ unsigned int gcnt[PPB];
  const int t    = threadIdx.x;
  const int b    = blockIdx.x / BPBK;
  const int pb   = blockIdx.x % BPBK;
  const int g    = t >> 4;         // group (0..15)
  const int sub  = t & 15;         // lane within group
  const int ib   = pb * PPB + g * PPG;   // first of my group's 4 points
  const float* base = xyz1 + (size_t)b * NN * 3;

  float px[PPG], py[PPG], pz[PPG];
#pragma unroll
  for (int p = 0; p < PPG; ++p) {
    px[p] = base[3 * (ib + p)];
    py[p] = base[3 * (ib + p) + 1];
    pz[p] = base[3 * (ib + p) + 2];
  }

  // ---- pass 1: 4 max-accumulators per point per lane ----
  float acc[PPG][4];
#pragma unroll
  for (int p = 0; p < PPG; ++p)
#pragma unroll
    for (int r = 0; r < 4; ++r) acc[p][r] = -INFINITY;

  for (int t0 = 0; t0 < NN; t0 += TILE) {
    for (int pp = t; pp < TILE; pp += TPB) {
      int j = t0 + pp;
      float x = base[3 * j], y = base[3 * j + 1], z = base[3 * j + 2];
      tile[pp] = make_float4(x, y, z, __fmul_rn(-0.5f, sqnorm(x, y, z)));
    }
    __syncthreads();
    for (int k = 0; k < TILE / GPP; k += 4) {
      float4 q0 = tile[sub + (k + 0) * GPP];
      float4 q1 = tile[sub + (k + 1) * GPP];
      float4 q2 = tile[sub + (k + 2) * GPP];
      float4 q3 = tile[sub + (k + 3) * GPP];
#pragma unroll
      for (int p = 0; p < PPG; ++p) {
        acc[p][0] = fmaxf(acc[p][0], score_s(q0.x, q0.y, q0.z, q0.w, px[p], py[p], pz[p]));
        acc[p][1] = fmaxf(acc[p][1], score_s(q1.x, q1.y, q1.z, q1.w, px[p], py[p], pz[p]));
        acc[p][2] = fmaxf(acc[p][2], score_s(q2.x, q2.y, q2.z, q2.w, px[p], py[p], pz[p]));
        acc[p][3] = fmaxf(acc[p][3], score_s(q3.x, q3.y, q3.z, q3.w, px[p], py[p], pz[p]));
      }
    }
    __syncthreads();
  }

  // ---- per point: sort 4 accs desc, 16-lane dup-agnostic pop-merge -> thr ----
  float thrp[PPG];
#pragma unroll
  for (int p = 0; p < PPG; ++p) {
    float c0 = acc[p][0], c1 = acc[p][1], c2 = acc[p][2], c3 = acc[p][3];
    CSWAPFD(c0, c1) CSWAPFD(c2, c3) CSWAPFD(c0, c2) CSWAPFD(c1, c3) CSWAPFD(c1, c2)
    float m = c0;
#pragma unroll
    for (int r = 0; r < KK; ++r) {
      m = c0;
      m = fmaxf(m, __shfl_xor(m, 1));
      m = fmaxf(m, __shfl_xor(m, 2));
      m = fmaxf(m, __shfl_xor(m, 4));
      m = fmaxf(m, __shfl_xor(m, 8));
      if (c0 == m) { c0 = c1; c1 = c2; c2 = c3; c3 = -INFINITY; }  // bound only widens
    }
    thrp[p] = m;   // thr <= true 10th-largest s (valid bound; pass2+sort restore exact)
  }

  // ---- pass 2: collect s >= thr into per-point buffers ----
  if (t < PPB) gcnt[t] = 0;
  __syncthreads();

  for (int t0 = 0; t0 < NN; t0 += TILE) {
    for (int pp = t; pp < TILE; pp += TPB) {
      int j = t0 + pp;
      float x = base[3 * j], y = base[3 * j + 1], z = base[3 * j + 2];
      tile[pp] = make_float4(x, y, z, __fmul_rn(-0.5f, sqnorm(x, y, z)));
    }
    __syncthreads();
#pragma unroll 4
    for (int c = sub; c < TILE; c += GPP) {
      float4 q = tile[c];
#pragma unroll
      for (int p = 0; p < PPG; ++p) {
        float s = score_s(q.x, q.y, q.z, q.w, px[p], py[p], pz[p]);
        if (s >= thrp[p]) {
          unsigned long long key = s_key(s, t0 + c);
          unsigned pos = atomicAdd(&gcnt[g * PPG + p], 1u);
          if (pos < (unsigned)CAP) gbuf[g * PPG + p][pos] = key;
        }
      }
    }
    __syncthreads();
  }

  // ---- final: per point, exact sort of <=48 keys; exact fallback if overflow ----
  const int gidbase = b * NN + ib;
  for (int p = 0; p < PPG; ++p) {
    const int pt = g * PPG + p;
    const unsigned cnt = gcnt[pt];
    if (cnt <= (unsigned)CAP) {
      unsigned long long e0 = (sub      < (int)cnt) ? gbuf[pt][sub]      : ~0ULL;
      unsigned long long e1 = (sub + 16 < (int)cnt) ? gbuf[pt][sub + 16] : ~0ULL;
      unsigned long long e2 = (sub + 32 < (int)cnt) ? gbuf[pt][sub + 32] : ~0ULL;
      CSWAPU(e0, e1) CSWAPU(e1, e2) CSWAPU(e0, e1)
#pragma unroll
      for (int r = 0; r < KK; ++r) {
        unsigned long long m = e0, o;
        o = __shfl_xor(m, 1); m = (o < m) ? o : m;
        o = __shfl_xor(m, 2); m = (o < m) ? o : m;
        o = __shfl_xor(m, 4); m = (o < m) ? o : m;
        o = __shfl_xor(m, 8); m = (o < m) ? o : m;
        if (e0 == m) { e0 = e1; e1 = e2; e2 = ~0ULL; }  // keys unique -> one lane pops
        if (sub == (r & 15)) idxbuf[(gidbase + p) * KK + r] = (int)(unsigned)(m & 0xFFFFFFFFULL);
      }
    } else {
      // exact fallback (essentially never): 16-lane u64 top-10 over global for this point
      unsigned long long k0 = ~0ULL, k1 = ~0ULL, k2 = ~0ULL, k3 = ~0ULL, k4 = ~0ULL,
                         k5 = ~0ULL, k6 = ~0ULL, k7 = ~0ULL, k8 = ~0ULL, k9 = ~0ULL;
      for (int c = sub; c < NN; c += GPP) {
        float x = base[3 * c], y = base[3 * c + 1], z = base[3 * c + 2];
        float s = score_s(x, y, z, __fmul_rn(-0.5f, sqnorm(x, y, z)), px[p], py[p], pz[p]);
        unsigned long long key = s_key(s, c);
        if (key < k9) {
          unsigned long long x2 = key;
          { unsigned long long &x = x2;
            INS2(k0) INS2(k1) INS2(k2) INS2(k3) INS2(k4)
            INS2(k5) INS2(k6) INS2(k7) INS2(k8) INS2(k9) }
        }
      }
#pragma unroll
      for (int r = 0; r < KK; ++r) {
        unsigned long long m = k0, o;
        o = __shfl_xor(m, 1); m = (o < m) ? o : m;
        o = __shfl_xor(m, 2); m = (o < m) ? o : m;
        o = __shfl_xor(m, 4); m = (o < m) ? o : m;
        o = __shfl_xor(m, 8); m = (o < m) ? o : m;
        if (k0 == m) { k0=k1;k1=k2;k2=k3;k3=k4;k4=k5;k5=k6;k6=k7;k7=k8;k8=k9;k9=~0ULL; }
        if (sub == (r & 15)) idxbuf[(gidbase + p) * KK + r] = (int)(unsigned)(m & 0xFFFFFFFFULL);
      }
    }
  }
}

// ---------------- Kernel 2: split-cloud SVD — 1 SVD per thread ----------------
__global__ __launch_bounds__(TPB, 1)
void lfl_svd(const float* __restrict__ xyz1, const float* __restrict__ xyz2,
             const int* __restrict__ idxbuf, double* __restrict__ partials) {
  __shared__ double pv[TPB];
  __shared__ double red1[128], red2[128];
  const int t = threadIdx.x;
  const int half = t >> 7;          // 0: cloud1, 1: cloud2
  const int lt = t & 127;
  const int pid = blockIdx.x * 128 + lt;   // point id 0..NPTS-1
  const int b = pid / NN, i = pid % NN;
  const float* basep = (half == 0) ? (xyz1 + (size_t)b * NN * 3)
                                   : (xyz2 + (size_t)b * NN * 3);
  double p;
  {
    double A[KK][3];
    double cx = 0, cy = 0, cz = 0;
#pragma unroll
    for (int s = 0; s < KK; ++s) {
      int j = idxbuf[pid * KK + s];
      j = ((unsigned)j < (unsigned)NN) ? j : 0;   // defensive: fault -> numeric miss
      A[s][0] = (double)basep[3 * j];
      A[s][1] = (double)basep[3 * j + 1];
      A[s][2] = (double)basep[3 * j + 2];
      cx += A[s][0]; cy += A[s][1]; cz += A[s][2];
    }
    cx *= 0.1; cy *= 0.1; cz *= 0.1;
#pragma unroll
    for (int s = 0; s < KK; ++s) { A[s][0] -= cx; A[s][1] -= cy; A[s][2] -= cz; }
    double nx, ny, nz;
    lapack_normal(A, nx, ny, nz);
    p = ((double)basep[3 * i] - cx) * nx + ((double)basep[3 * i + 1] - cy) * ny +
        ((double)basep[3 * i + 2] - cz) * nz;
  }
  pv[t] = p;
  __syncthreads();

  if (t < 128) {
    double p1 = pv[t], p2 = pv[t + 128];
    double da = fabs(p1) - fabs(p2);
    double df = p2 - p1;
    double bent = df > 0.0 ? df : 0.0;
    red1[t] = da * da;
    red2[t] = bent * bent;
  }
  __syncthreads();
  for (int s = 64; s > 0; s >>= 1) {
    if (t < s) { red1[t] += red1[t + s]; red2[t] += red2[t + s]; }
    __syncthreads();
  }
  if (t == 0) {
    partials[2 * blockIdx.x]     = red1[0];
    partials[2 * blockIdx.x + 1] = red2[0];
  }
}

// ---------------- Kernel 3: parallel deterministic finalize ----------------
__global__ __launch_bounds__(TPB)
void lfl_final(const double* __restrict__ partials, float* __restrict__ out) {
  __shared__ double r1[TPB], r2[TPB];
  const int t = threadIdx.x;
  r1[t] = partials[2 * t];
  r2[t] = partials[2 * t + 1];
  __syncthreads();
  for (int s = TPB / 2; s > 0; s >>= 1) {
    if (t < s) { r1[t] += r1[t + s]; r2[t] += r2[t + s]; }
    __syncthreads();
  }
  if (t == 0) out[0] = (float)((r1[0] + 5.0 * r2[0]) / (double)NPTS);
}

extern "C" void kernel_launch(void* const* d_in, const int* in_sizes, int n_in,
                              void* d_out, int out_size, void* d_ws, size_t ws_size,
                              hipStream_t stream) {
  const float* xyz1 = (const float*)d_in[0];
  const float* xyz2 = (const float*)d_in[1];
  float* out = (float*)d_out;
  double* partials = (double*)d_ws;                      // 4 KB
  int* idxbuf = (int*)((char*)d_ws + 4096);              // 1.31 MB

  lfl_knn<<<KNBLK, TPB, 0, stream>>>(xyz1, idxbuf);
  lfl_svd<<<SVDBLK, TPB, 0, stream>>>(xyz1, xyz2, idxbuf, partials);
  lfl_final<<<1, TPB, 0, stream>>>(partials, out);
}

// Round 14
// 111.601 us; speedup vs baseline: 1.1334x; 1.1334x over previous
//
#include <hip/hip_runtime.h>
#include <math.h>

#define BB   8
#define NN   4096
#define KK   10
#define TPB  256
#define NPTS (BB * NN)      // 32768

// KNN decomposition: 16 lanes per point, 16 points per block (R12 structure)
#define GPP  16
#define PPB  (TPB / GPP)            // 16
#define BPBK (NN / PPB)             // 256 blocks per batch
#define KNBLK (BB * BPBK)           // 2048 blocks
#define TILE 1024                   // R14: 2x tile -> half the barriers
#define CAP  48                     // pass-2 buffer slots per group

// SVD-side: 256 blocks, each covers 128 points x {cloud1, cloud2}
#define SVDBLK 256
#define SBLK   256                  // partials entries

// --- LAPACK environment constants (reference = numpy float32 sgesdd) ---
#define LARTG_OLD 0
#define EPSV  5.9604644775390625e-8    // 2^-24
#define UNFLV 1.1754943508222875e-38   // 2^-126
#define TOLV (10.0 * EPSV)

static __device__ __forceinline__ double lapy2d(double x, double y) {
  double xa = fabs(x), ya = fabs(y);
  double w = fmax(xa, ya), z = fmin(xa, ya);
  if (z == 0.0) return w;
  double q = z / w;
  return w * sqrt(1.0 + q * q);
}

static __device__ __forceinline__ void lartg(double f, double g,
                                             double &c, double &s, double &r) {
#if LARTG_OLD
  if (g == 0.0) { c = 1.0; s = 0.0; r = f; }
  else if (f == 0.0) { c = 0.0; s = 1.0; r = g; }
  else {
    double d = sqrt(f * f + g * g);
    c = f / d; s = g / d; r = d;
    if (fabs(f) > fabs(g) && c < 0.0) { c = -c; s = -s; r = -r; }
  }
#else
  if (g == 0.0) { c = 1.0; s = 0.0; r = f; }
  else if (f == 0.0) { c = 0.0; s = copysign(1.0, g); r = fabs(g); }
  else {
    double d = sqrt(f * f + g * g);
    c = fabs(f) / d;
    r = copysign(d, f);
    s = g / r;
  }
#endif
}

static __device__ void las2(double f, double g, double h, double &ssmin, double &ssmax) {
  double fa = fabs(f), ga = fabs(g), ha = fabs(h);
  double fhmn = fmin(fa, ha), fhmx = fmax(fa, ha);
  if (fhmn == 0.0) {
    ssmin = 0.0;
    if (fhmx == 0.0) ssmax = ga;
    else {
      double mn = fmin(fhmx, ga), mx = fmax(fhmx, ga);
      double rr = mn / mx;
      ssmax = mx * sqrt(1.0 + rr * rr);
    }
  } else {
    if (ga < fhmx) {
      double as_ = 1.0 + fhmn / fhmx;
      double at  = (fhmx - fhmn) / fhmx;
      double au  = (ga / fhmx); au = au * au;
      double c   = 2.0 / (sqrt(as_ * as_ + au) + sqrt(at * at + au));
      ssmin = fhmn * c;
      ssmax = fhmx / c;
    } else {
      double au = fhmx / ga;
      if (au == 0.0) { ssmin = (fhmn * fhmx) / ga; ssmax = ga; }
      else {
        double as_ = 1.0 + fhmn / fhmx;
        double at  = (fhmx - fhmn) / fhmx;
        double t1 = as_ * au, t2 = at * au;
        double c = 1.0 / (sqrt(1.0 + t1 * t1) + sqrt(1.0 + t2 * t2));
        ssmin = (fhmn * c) * au; ssmin = ssmin + ssmin;
        ssmax = ga / (c + c);
      }
    }
  }
}

static __device__ void lasv2(double f, double g, double h,
                             double &ssmin, double &ssmax,
                             double &snr, double &csr, double &snl, double &csl) {
  double ft = f, fa = fabs(f), ht = h, ha = fabs(h);
  int pmax = 1;
  bool swp = (ha > fa);
  if (swp) { pmax = 3; double t = ft; ft = ht; ht = t; t = fa; fa = ha; ha = t; }
  double gt = g, ga = fabs(g);
  double clt = 0, crt = 0, slt = 0, srt = 0;
  if (ga == 0.0) {
    ssmin = ha; ssmax = fa;
    clt = 1.0; crt = 1.0; slt = 0.0; srt = 0.0;
  } else {
    bool gasmal = true;
    if (ga > fa) {
      pmax = 2;
      if ((fa / ga) < EPSV) {
        gasmal = false;
        ssmax = ga;
        if (ha > 1.0) ssmin = fa / (ga / ha);
        else          ssmin = (fa / ga) * ha;
        clt = 1.0; slt = ht / gt; srt = 1.0; crt = ft / gt;
      }
    }
    if (gasmal) {
      double dd = fa - ha, l;
      if (dd == fa) l = 1.0; else l = dd / fa;
      double mv = gt / ft;
      double t = 2.0 - l;
      double mm = mv * mv, tt = t * t;
      double s = sqrt(tt + mm);
      double r = (l == 0.0) ? fabs(mv) : sqrt(l * l + mm);
      double a = 0.5 * (s + r);
      ssmin = ha / a;
      ssmax = fa * a;
      if (mm == 0.0) {
        if (l == 0.0) t = copysign(2.0, ft) * copysign(1.0, gt);
        else          t = gt / copysign(dd, ft) + mv / t;
      } else {
        t = (mv / (s + t) + mv / (r + l)) * (1.0 + a);
      }
      double lq = sqrt(t * t + 4.0);
      crt = 2.0 / lq;
      srt = t / lq;
      clt = (crt + srt * mv) / a;
      slt = (ht / ft) * srt / a;
    }
  }
  if (swp) { csl = srt; snl = crt; csr = slt; snr = clt; }
  else     { csl = clt; snl = slt; csr = crt; snr = srt; }
  double tsign = 1.0;
  if (pmax == 1) tsign = copysign(1.0, csr) * copysign(1.0, csl) * copysign(1.0, f);
  if (pmax == 2) tsign = copysign(1.0, snr) * copysign(1.0, csl) * copysign(1.0, g);
  if (pmax == 3) tsign = copysign(1.0, snr) * copysign(1.0, snl) * copysign(1.0, h);
  ssmax = copysign(ssmax, tsign);
  ssmin = copysign(ssmin, tsign * copysign(1.0, f) * copysign(1.0, h));
}

static __device__ __forceinline__ void rot_rows(double vt[3][3], int lo, double c, double s) {
  if (c != 1.0 || s != 0.0) {
    for (int k = 0; k < 3; ++k) {
      double tp = vt[lo + 1][k];
      vt[lo + 1][k] = c * tp - s * vt[lo][k];
      vt[lo][k]     = s * tp + c * vt[lo][k];
    }
  }
}

static __device__ void bdsqr3(double d[3], double e[2], double vt[3][3]) {
  const double tol = TOLV;
  double sminoa = fabs(d[0]);
  if (sminoa != 0.0) {
    double mu = sminoa;
    mu = fabs(d[1]) * (mu / (mu + fabs(e[0])));
    sminoa = fmin(sminoa, mu);
    if (sminoa != 0.0) {
      mu = fabs(d[2]) * (mu / (mu + fabs(e[1])));
      sminoa = fmin(sminoa, mu);
    }
  }
  sminoa /= sqrt(3.0);
  double thresh = fmax(tol * sminoa, 54.0 * UNFLV);
  int m = 3, oldll = -1, oldm = -1, idir = 0;
  double sminl = 0.0;
  for (int guard = 0; guard < 500 && m > 1; ++guard) {
    double smax = fabs(d[m - 1]);
    int ll = 0;
    bool split = false;
    for (int lll = 1; lll <= m - 1; ++lll) {
      int l = m - lll;
      double abss = fabs(d[l - 1]);
      double abse = fabs(e[l - 1]);
      if (abse <= thresh) { ll = l; split = true; break; }
      smax = fmax(smax, fmax(abss, abse));
    }
    if (split) {
      e[ll - 1] = 0.0;
      if (ll == m - 1) { m = m - 1; continue; }
      ll = ll + 1;
    } else ll = 1;
    if (ll == m - 1) {
      double sigmn, sigmx, sinr, cosr, sinl, cosl;
      lasv2(d[m - 2], e[m - 2], d[m - 1], sigmn, sigmx, sinr, cosr, sinl, cosl);
      d[m - 2] = sigmx; e[m - 2] = 0.0; d[m - 1] = sigmn;
      for (int k = 0; k < 3; ++k) {
        double x = vt[m - 2][k], y = vt[m - 1][k];
        vt[m - 2][k] = cosr * x + sinr * y;
        vt[m - 1][k] = cosr * y - sinr * x;
      }
      m -= 2;
      continue;
    }
    if (ll > oldm || m < oldll)
      idir = (fabs(d[ll - 1]) >= fabs(d[m - 1])) ? 1 : 2;
    bool deflated = false;
    if (idir == 1) {
      if (fabs(e[m - 2]) <= tol * fabs(d[m - 1])) { e[m - 2] = 0.0; continue; }
      double mu = fabs(d[ll - 1]);
      sminl = mu;
      for (int lll = ll; lll <= m - 1; ++lll) {
        if (fabs(e[lll - 1]) <= tol * mu) { e[lll - 1] = 0.0; deflated = true; break; }
        mu = fabs(d[lll]) * (mu / (mu + fabs(e[lll - 1])));
        sminl = fmin(sminl, mu);
      }
    } else {
      if (fabs(e[ll - 1]) <= tol * fabs(d[ll - 1])) { e[ll - 1] = 0.0; continue; }
      double mu = fabs(d[m - 1]);
      sminl = mu;
      for (int lll = m - 1; lll >= ll; --lll) {
        if (fabs(e[lll - 1]) <= tol * mu) { e[lll - 1] = 0.0; deflated = true; break; }
        mu = fabs(d[lll - 1]) * (mu / (mu + fabs(e[lll - 1])));
        sminl = fmin(sminl, mu);
      }
    }
    if (deflated) continue;
    oldll = ll; oldm = m;
    double shift = 0.0, rdum = 0.0;
    if (!(3.0 * tol * (sminl / smax) <= fmax(EPSV, 0.01 * tol))) {
      double sll;
      if (idir == 1) { sll = fabs(d[ll - 1]); las2(d[m - 2], e[m - 2], d[m - 1], shift, rdum); }
      else           { sll = fabs(d[m - 1]); las2(d[ll - 1], e[ll - 1], d[ll], shift, rdum); }
      if (sll > 0.0 && (shift / sll) * (shift / sll) < EPSV) shift = 0.0;
    }
    double csv[2], snv[2];
    if (shift == 0.0) {
      if (idir == 1) {
        double cs = 1.0, oldcs = 1.0, sn = 0.0, oldsn = 0.0, r = 0.0;
        for (int i = ll; i <= m - 1; ++i) {
          lartg(d[i - 1] * cs, e[i - 1], cs, sn, r);
          if (i > ll) e[i - 2] = oldsn * r;
          lartg(oldcs * r, d[i] * sn, oldcs, oldsn, d[i - 1]);
          csv[i - ll] = cs; snv[i - ll] = sn;
        }
        double h = d[m - 1] * cs;
        d[m - 1] = h * oldcs;
        e[m - 2] = h * oldsn;
        for (int j = 0; j <= m - ll - 1; ++j) rot_rows(vt, ll - 1 + j, csv[j], snv[j]);
        if (fabs(e[m - 2]) <= thresh) e[m - 2] = 0.0;
      } else {
        double cs = 1.0, oldcs = 1.0, sn = 0.0, oldsn = 0.0, r = 0.0;
        for (int i = m; i >= ll + 1; --i) {
          lartg(d[i - 1] * cs, e[i - 2], cs, sn, r);
          if (i < m) e[i - 1] = oldsn * r;
          lartg(oldcs * r, d[i - 2] * sn, oldcs, oldsn, d[i - 1]);
          csv[i - ll - 1] = oldcs; snv[i - ll - 1] = -oldsn;
        }
        double h = d[ll - 1] * cs;
        d[ll - 1] = h * oldcs;
        e[ll - 1] = h * oldsn;
        for (int j = m - ll - 1; j >= 0; --j) rot_rows(vt, ll - 1 + j, csv[j], snv[j]);
        if (fabs(e[ll - 1]) <= thresh) e[ll - 1] = 0.0;
      }
    } else {
      if (idir == 1) {
        double f = (fabs(d[ll - 1]) - shift) * (copysign(1.0, d[ll - 1]) + shift / d[ll - 1]);
        double g = e[ll - 1], cosr, sinr, cosl, sinl, r;
        for (int i = ll; i <= m - 1; ++i) {
          lartg(f, g, cosr, sinr, r);
          if (i > ll) e[i - 2] = r;
          f = cosr * d[i - 1] + sinr * e[i - 1];
          e[i - 1] = cosr * e[i - 1] - sinr * d[i - 1];
          g = sinr * d[i];
          d[i] = cosr * d[i];
          lartg(f, g, cosl, sinl, r);
          d[i - 1] = r;
          f = cosl * e[i - 1] + sinl * d[i];
          d[i] = cosl * d[i] - sinl * e[i - 1];
          if (i < m - 1) { g = sinl * e[i]; e[i] = cosl * e[i]; }
          csv[i - ll] = cosr; snv[i - ll] = sinr;
        }
        e[m - 2] = f;
        for (int j = 0; j <= m - ll - 1; ++j) rot_rows(vt, ll - 1 + j, csv[j], snv[j]);
        if (fabs(e[m - 2]) <= thresh) e[m - 2] = 0.0;
      } else {
        double f = (fabs(d[m - 1]) - shift) * (copysign(1.0, d[m - 1]) + shift / d[m - 1]);
        double g = e[m - 2], cosr, sinr, cosl, sinl, r;
        for (int i = m; i >= ll + 1; --i) {
          lartg(f, g, cosr, sinr, r);
          if (i < m) e[i - 1] = r;
          f = cosr * d[i - 1] + sinr * e[i - 2];
          e[i - 2] = cosr * e[i - 2] - sinr * d[i - 1];
          g = sinr * d[i - 2];
          d[i - 2] = cosr * d[i - 2];
          lartg(f, g, cosl, sinl, r);
          d[i - 1] = r;
          f = cosl * e[i - 2] + sinl * d[i - 2];
          d[i - 2] = cosl * d[i - 2] - sinl * e[i - 2];
          if (i > ll + 1) { g = sinl * e[i - 3]; e[i - 3] = cosl * e[i - 3]; }
          csv[i - ll - 1] = cosr; snv[i - ll - 1] = sinr;
        }
        e[ll - 1] = f;
        for (int j = m - ll - 1; j >= 0; --j) rot_rows(vt, ll - 1 + j, csv[j], snv[j]);
        if (fabs(e[ll - 1]) <= thresh) e[ll - 1] = 0.0;
      }
    }
  }
  for (int i = 0; i < 3; ++i)
    if (d[i] < 0.0) { d[i] = -d[i]; for (int k = 0; k < 3; ++k) vt[i][k] = -vt[i][k]; }
}

static __device__ void lapack_normal(double A[KK][3], double &nx, double &ny, double &nz) {
#pragma unroll
  for (int i = 0; i < 3; ++i) {
    double ss = 0.0;
#pragma unroll
    for (int j = i + 1; j < KK; ++j) ss += A[j][i] * A[j][i];
    double xnorm = sqrt(ss);
    if (xnorm != 0.0) {
      double alpha = A[i][i];
      double beta = -copysign(lapy2d(alpha, xnorm), alpha);
      double tau = (beta - alpha) / beta;
      double sc = 1.0 / (alpha - beta);
#pragma unroll
      for (int j = i + 1; j < KK; ++j) A[j][i] *= sc;
      A[i][i] = beta;
#pragma unroll
      for (int c = i + 1; c < 3; ++c) {
        double w = A[i][c];
#pragma unroll
        for (int j = i + 1; j < KK; ++j) w += A[j][i] * A[j][c];
        w *= tau;
        A[i][c] -= w;
#pragma unroll
        for (int j = i + 1; j < KK; ++j) A[j][c] -= w * A[j][i];
      }
    }
  }
  double r11 = A[0][0], r12 = A[0][1], r13 = A[0][2];
  double r22 = A[1][1], r23 = A[1][2], r33 = A[2][2];
  double d[3], e[2];
  double taup1 = 0.0, v3 = 0.0;
  d[0] = r11;
  double a22 = r22, a23 = r23, a32 = 0.0, a33 = r33;
  if (r13 != 0.0) {
    double betap = -copysign(lapy2d(r12, r13), r12);
    taup1 = (betap - r12) / betap;
    v3 = r13 / (r12 - betap);
    e[0] = betap;
    double w2 = (a22 + a23 * v3) * taup1;
    a22 -= w2; a23 -= w2 * v3;
    double w3 = (a33 * v3) * taup1;
    a32 = -w3; a33 -= w3 * v3;
  } else {
    e[0] = r12;
  }
  if (a32 != 0.0) {
    double beta2 = -copysign(lapy2d(a22, a32), a22);
    double tq = (beta2 - a22) / beta2;
    double v2 = a32 / (a22 - beta2);
    d[1] = beta2;
    double w = (a23 + v2 * a33) * tq;
    a23 -= w; a33 -= w * v2;
  } else d[1] = a22;
  e[1] = a23;
  d[2] = a33;
  double vt[3][3] = {{1,0,0},{0,1,0},{0,0,1}};
  bdsqr3(d, e, vt);
  int im = 0;
  if (d[1] < d[im]) im = 1;
  if (d[2] < d[im]) im = 2;
  double w1 = vt[im][0], w2 = vt[im][1], w3 = vt[im][2];
  double sdot = (w2 + w3 * v3) * taup1;
  w2 -= sdot; w3 -= sdot * v3;
  double inv = 1.0 / sqrt(w1 * w1 + w2 * w2 + w3 * w3);
  nx = w1 * inv; ny = w2 * inv; nz = w3 * inv;
}

// ---------------- Kernel 1: s-space probe-bound two-pass KNN (16 lanes/point) ----------------
// s = dot(p, q) - 0.5|q|^2  is monotone-DECREASING in dd = |p|^2 - 2s.
// Top-10 smallest dd == top-10 largest s. Probe with max-accs; collect s >= thr.
#define INS2(Kp) { bool lt_ = x < Kp; unsigned long long old_ = Kp; Kp = lt_ ? x : Kp; x = lt_ ? old_ : x; }
#define CSWAPU(U,V) { if (V < U) { unsigned long long t_ = U; U = V; V = t_; } }
#define CSWAPFD(U,V) { float mx_ = fmaxf(U, V); V = fminf(U, V); U = mx_; }   // descending

// pinned score: identical instruction sequence everywhere (qw = -0.5*|q|^2)
static __device__ __forceinline__ float score_s(float qx, float qy, float qz, float qw,
                                                float xi, float yi, float zi) {
  return fmaf(xi, qx, fmaf(yi, qy, fmaf(zi, qz, qw)));
}
static __device__ __forceinline__ float sqnorm(float x, float y, float z) {
  return __fadd_rn(__fadd_rn(__fmul_rn(x, x), __fmul_rn(y, y)), __fmul_rn(z, z));
}
// key: ascending-u64 order == (s descending, idx ascending) == top_k order
static __device__ __forceinline__ unsigned long long s_key(float s, int idx) {
  unsigned u = __float_as_uint(s);
  u = (u & 0x80000000u) ? ~u : (u | 0x80000000u);   // monotone increasing in s
  return ((unsigned long long)(~u) << 32) | (unsigned)idx;
}

__global__ __launch_bounds__(TPB, 1)
void lfl_knn(const float* __restrict__ xyz1, int* __restrict__ idxbuf) {
  __shared__ float4 tile[TILE];                       // 16 KB
  __shared__ unsigned long long gbuf[PPB][CAP];       // 6 KB
  __shared__ unsigned int gcnt[PPB];
  const int t    = threadIdx.x;
  const int b    = blockIdx.x / BPBK;
  const int pb   = blockIdx.x % BPBK;
  const int g    = t >> 4;         // point group within block (0..15)
  const int sub  = t & 15;         // lane within group
  const int i    = pb * PPB + g;
  const float* base = xyz1 + (size_t)b * NN * 3;

  const float xi = base[3 * i], yi = base[3 * i + 1], zi = base[3 * i + 2];

  // ---- pass 1: 8 independent max-accumulators per lane (1 fmaxf/candidate) ----
  float b0 = -INFINITY, b1 = -INFINITY, b2 = -INFINITY, b3 = -INFINITY,
        b4 = -INFINITY, b5 = -INFINITY, b6 = -INFINITY, b7 = -INFINITY;

  for (int t0 = 0; t0 < NN; t0 += TILE) {
    for (int p = t; p < TILE; p += TPB) {
      int j = t0 + p;
      float x = base[3 * j], y = base[3 * j + 1], z = base[3 * j + 2];
      tile[p] = make_float4(x, y, z, __fmul_rn(-0.5f, sqnorm(x, y, z)));
    }
    __syncthreads();
    for (int k = 0; k < TILE / GPP; k += 8) {
      float4 q0 = tile[sub + (k + 0) * GPP];
      float4 q1 = tile[sub + (k + 1) * GPP];
      float4 q2 = tile[sub + (k + 2) * GPP];
      float4 q3 = tile[sub + (k + 3) * GPP];
      float4 q4 = tile[sub + (k + 4) * GPP];
      float4 q5 = tile[sub + (k + 5) * GPP];
      float4 q6 = tile[sub + (k + 6) * GPP];
      float4 q7 = tile[sub + (k + 7) * GPP];
      b0 = fmaxf(b0, score_s(q0.x, q0.y, q0.z, q0.w, xi, yi, zi));
      b1 = fmaxf(b1, score_s(q1.x, q1.y, q1.z, q1.w, xi, yi, zi));
      b2 = fmaxf(b2, score_s(q2.x, q2.y, q2.z, q2.w, xi, yi, zi));
      b3 = fmaxf(b3, score_s(q3.x, q3.y, q3.z, q3.w, xi, yi, zi));
      b4 = fmaxf(b4, score_s(q4.x, q4.y, q4.z, q4.w, xi, yi, zi));
      b5 = fmaxf(b5, score_s(q5.x, q5.y, q5.z, q5.w, xi, yi, zi));
      b6 = fmaxf(b6, score_s(q6.x, q6.y, q6.z, q6.w, xi, yi, zi));
      b7 = fmaxf(b7, score_s(q7.x, q7.y, q7.z, q7.w, xi, yi, zi));
    }
    __syncthreads();
  }
  // descending Batcher-8 sort (19 compares), once per point
  CSWAPFD(b0, b1) CSWAPFD(b2, b3) CSWAPFD(b4, b5) CSWAPFD(b6, b7)
  CSWAPFD(b0, b2) CSWAPFD(b1, b3) CSWAPFD(b4, b6) CSWAPFD(b5, b7)
  CSWAPFD(b1, b2) CSWAPFD(b5, b6)
  CSWAPFD(b0, b4) CSWAPFD(b1, b5) CSWAPFD(b2, b6) CSWAPFD(b3, b7)
  CSWAPFD(b2, b4) CSWAPFD(b3, b5)
  CSWAPFD(b1, b2) CSWAPFD(b3, b4) CSWAPFD(b5, b6)

  // ---- dup-agnostic pop-merge (max) over 128-value union: thr <= true 10th-largest s ----
  float thr;
  {
    float m = b0;
#pragma unroll
    for (int r = 0; r < KK; ++r) {
      m = b0;
      m = fmaxf(m, __shfl_xor(m, 1));
      m = fmaxf(m, __shfl_xor(m, 2));
      m = fmaxf(m, __shfl_xor(m, 4));
      m = fmaxf(m, __shfl_xor(m, 8));
      if (b0 == m) { b0 = b1; b1 = b2; b2 = b3; b3 = b4; b4 = b5; b5 = b6; b6 = b7; b7 = -INFINITY; }
    }
    thr = m;   // dup lanes pop together: bound only falls -> still a valid (wider) bound
  }

  // ---- pass 2: collect all s >= thr ----
  if (sub == 0) gcnt[g] = 0;
  __syncthreads();

  for (int t0 = 0; t0 < NN; t0 += TILE) {
    for (int p = t; p < TILE; p += TPB) {
      int j = t0 + p;
      float x = base[3 * j], y = base[3 * j + 1], z = base[3 * j + 2];
      tile[p] = make_float4(x, y, z, __fmul_rn(-0.5f, sqnorm(x, y, z)));
    }
    __syncthreads();
#pragma unroll 8
    for (int c = sub; c < TILE; c += GPP) {
      float4 q = tile[c];
      float s = score_s(q.x, q.y, q.z, q.w, xi, yi, zi);
      if (s >= thr) {
        unsigned long long key = s_key(s, t0 + c);
        unsigned pos = atomicAdd(&gcnt[g], 1u);
        if (pos < (unsigned)CAP) gbuf[g][pos] = key;
      }
    }
    __syncthreads();
  }

  const unsigned cnt = gcnt[g];
  const int gid = b * NN + i;

  if (cnt <= (unsigned)CAP) {
    // ---- sort <=48 keys with 16 lanes (3-deep sorted per lane + pop-merge) ----
    unsigned long long e0 = (sub      < (int)cnt) ? gbuf[g][sub]      : ~0ULL;
    unsigned long long e1 = (sub + 16 < (int)cnt) ? gbuf[g][sub + 16] : ~0ULL;
    unsigned long long e2 = (sub + 32 < (int)cnt) ? gbuf[g][sub + 32] : ~0ULL;
    CSWAPU(e0, e1) CSWAPU(e1, e2) CSWAPU(e0, e1)
#pragma unroll
    for (int r = 0; r < KK; ++r) {
      unsigned long long m = e0, o;
      o = __shfl_xor(m, 1); m = (o < m) ? o : m;
      o = __shfl_xor(m, 2); m = (o < m) ? o : m;
      o = __shfl_xor(m, 4); m = (o < m) ? o : m;
      o = __shfl_xor(m, 8); m = (o < m) ? o : m;
      if (e0 == m) { e0 = e1; e1 = e2; e2 = ~0ULL; }  // keys unique -> exactly one lane pops
      if (sub == (r & 15)) idxbuf[gid * KK + r] = (int)(unsigned)(m & 0xFFFFFFFFULL);
    }
  } else {
    // ---- exact fallback (essentially never): per-lane u64 top-10 over global ----
    unsigned long long k0 = ~0ULL, k1 = ~0ULL, k2 = ~0ULL, k3 = ~0ULL, k4 = ~0ULL,
                       k5 = ~0ULL, k6 = ~0ULL, k7 = ~0ULL, k8 = ~0ULL, k9 = ~0ULL;
    for (int c = sub; c < NN; c += GPP) {
      float x = base[3 * c], y = base[3 * c + 1], z = base[3 * c + 2];
      float s = score_s(x, y, z, __fmul_rn(-0.5f, sqnorm(x, y, z)), xi, yi, zi);
      unsigned long long key = s_key(s, c);
      if (key < k9) {
        unsigned long long x2 = key;
        { unsigned long long &x = x2;
          INS2(k0) INS2(k1) INS2(k2) INS2(k3) INS2(k4)
          INS2(k5) INS2(k6) INS2(k7) INS2(k8) INS2(k9) }
      }
    }
#pragma unroll
    for (int r = 0; r < KK; ++r) {
      unsigned long long m = k0, o;
      o = __shfl_xor(m, 1); m = (o < m) ? o : m;
      o = __shfl_xor(m, 2); m = (o < m) ? o : m;
      o = __shfl_xor(m, 4); m = (o < m) ? o : m;
      o = __shfl_xor(m, 8); m = (o < m) ? o : m;
      if (k0 == m) { k0=k1;k1=k2;k2=k3;k3=k4;k4=k5;k5=k6;k6=k7;k7=k8;k8=k9;k9=~0ULL; }
      if (sub == (r & 15)) idxbuf[gid * KK + r] = (int)(unsigned)(m & 0xFFFFFFFFULL);
    }
  }
}

// ---------------- Kernel 2: split-cloud SVD — 1 SVD per thread ----------------
__global__ __launch_bounds__(TPB, 1)
void lfl_svd(const float* __restrict__ xyz1, const float* __restrict__ xyz2,
             const int* __restrict__ idxbuf, double* __restrict__ partials) {
  __shared__ double pv[TPB];
  __shared__ double red1[128], red2[128];
  const int t = threadIdx.x;
  const int half = t >> 7;          // 0: cloud1, 1: cloud2
  const int lt = t & 127;
  const int pid = blockIdx.x * 128 + lt;   // point id 0..NPTS-1
  const int b = pid / NN, i = pid % NN;
  const float* basep = (half == 0) ? (xyz1 + (size_t)b * NN * 3)
                                   : (xyz2 + (size_t)b * NN * 3);
  double p;
  {
    double A[KK][3];
    double cx = 0, cy = 0, cz = 0;
#pragma unroll
    for (int s = 0; s < KK; ++s) {
      int j = idxbuf[pid * KK + s];
      j = ((unsigned)j < (unsigned)NN) ? j : 0;   // defensive: fault -> numeric miss
      A[s][0] = (double)basep[3 * j];
      A[s][1] = (double)basep[3 * j + 1];
      A[s][2] = (double)basep[3 * j + 2];
      cx += A[s][0]; cy += A[s][1]; cz += A[s][2];
    }
    cx *= 0.1; cy *= 0.1; cz *= 0.1;
#pragma unroll
    for (int s = 0; s < KK; ++s) { A[s][0] -= cx; A[s][1] -= cy; A[s][2] -= cz; }
    double nx, ny, nz;
    lapack_normal(A, nx, ny, nz);
    p = ((double)basep[3 * i] - cx) * nx + ((double)basep[3 * i + 1] - cy) * ny +
        ((double)basep[3 * i + 2] - cz) * nz;
  }
  pv[t] = p;
  __syncthreads();

  if (t < 128) {
    double p1 = pv[t], p2 = pv[t + 128];
    double da = fabs(p1) - fabs(p2);
    double df = p2 - p1;
    double bent = df > 0.0 ? df : 0.0;
    red1[t] = da * da;
    red2[t] = bent * bent;
  }
  __syncthreads();
  for (int s = 64; s > 0; s >>= 1) {
    if (t < s) { red1[t] += red1[t + s]; red2[t] += red2[t + s]; }
    __syncthreads();
  }
  if (t == 0) {
    partials[2 * blockIdx.x]     = red1[0];
    partials[2 * blockIdx.x + 1] = red2[0];
  }
}

// ---------------- Kernel 3: parallel deterministic finalize ----------------
__global__ __launch_bounds__(TPB)
void lfl_final(const double* __restrict__ partials, float* __restrict__ out) {
  __shared__ double r1[TPB], r2[TPB];
  const int t = threadIdx.x;
  r1[t] = partials[2 * t];
  r2[t] = partials[2 * t + 1];
  __syncthreads();
  for (int s = TPB / 2; s > 0; s >>= 1) {
    if (t < s) { r1[t] += r1[t + s]; r2[t] += r2[t + s]; }
    __syncthreads();
  }
  if (t == 0) out[0] = (float)((r1[0] + 5.0 * r2[0]) / (double)NPTS);
}

extern "C" void kernel_launch(void* const* d_in, const int* in_sizes, int n_in,
                              void* d_out, int out_size, void* d_ws, size_t ws_size,
                              hipStream_t stream) {
  const float* xyz1 = (const float*)d_in[0];
  const float* xyz2 = (const float*)d_in[1];
  float* out = (float*)d_out;
  double* partials = (double*)d_ws;                      // 4 KB
  int* idxbuf = (int*)((char*)d_ws + 4096);              // 1.31 MB

  lfl_knn<<<KNBLK, TPB, 0, stream>>>(xyz1, idxbuf);
  lfl_svd<<<SVDBLK, TPB, 0, stream>>>(xyz1, xyz2, idxbuf, partials);
  lfl_final<<<1, TPB, 0, stream>>>(partials, out);
}

// Round 15
// 103.088 us; speedup vs baseline: 1.2270x; 1.0826x over previous
//
#include <hip/hip_runtime.h>
#include <math.h>

#define BB   8
#define NN   4096
#define KK   10
#define TPB  256
#define NPTS (BB * NN)      // 32768

// KNN decomposition: 16 lanes per point, 16 points per block (R12 structure)
#define GPP  16
#define PPB  (TPB / GPP)            // 16
#define BPBK (NN / PPB)             // 256 blocks per batch
#define KNBLK (BB * BPBK)           // 2048 blocks
#define TILE 512
#define CAP  48                     // pass-2 buffer slots per group

// SVD-side: 256 blocks, each covers 128 points x {cloud1, cloud2}
#define SVDBLK 256
#define SBLK   256                  // partials entries

// --- LAPACK environment constants (reference = numpy float32 sgesdd) ---
#define LARTG_OLD 0
#define EPSV  5.9604644775390625e-8    // 2^-24
#define UNFLV 1.1754943508222875e-38   // 2^-126
#define TOLV (10.0 * EPSV)

static __device__ __forceinline__ double lapy2d(double x, double y) {
  double xa = fabs(x), ya = fabs(y);
  double w = fmax(xa, ya), z = fmin(xa, ya);
  if (z == 0.0) return w;
  double q = z / w;
  return w * sqrt(1.0 + q * q);
}

static __device__ __forceinline__ void lartg(double f, double g,
                                             double &c, double &s, double &r) {
#if LARTG_OLD
  if (g == 0.0) { c = 1.0; s = 0.0; r = f; }
  else if (f == 0.0) { c = 0.0; s = 1.0; r = g; }
  else {
    double d = sqrt(f * f + g * g);
    c = f / d; s = g / d; r = d;
    if (fabs(f) > fabs(g) && c < 0.0) { c = -c; s = -s; r = -r; }
  }
#else
  if (g == 0.0) { c = 1.0; s = 0.0; r = f; }
  else if (f == 0.0) { c = 0.0; s = copysign(1.0, g); r = fabs(g); }
  else {
    double d = sqrt(f * f + g * g);
    c = fabs(f) / d;
    r = copysign(d, f);
    s = g / r;
  }
#endif
}

static __device__ void las2(double f, double g, double h, double &ssmin, double &ssmax) {
  double fa = fabs(f), ga = fabs(g), ha = fabs(h);
  double fhmn = fmin(fa, ha), fhmx = fmax(fa, ha);
  if (fhmn == 0.0) {
    ssmin = 0.0;
    if (fhmx == 0.0) ssmax = ga;
    else {
      double mn = fmin(fhmx, ga), mx = fmax(fhmx, ga);
      double rr = mn / mx;
      ssmax = mx * sqrt(1.0 + rr * rr);
    }
  } else {
    if (ga < fhmx) {
      double as_ = 1.0 + fhmn / fhmx;
      double at  = (fhmx - fhmn) / fhmx;
      double au  = (ga / fhmx); au = au * au;
      double c   = 2.0 / (sqrt(as_ * as_ + au) + sqrt(at * at + au));
      ssmin = fhmn * c;
      ssmax = fhmx / c;
    } else {
      double au = fhmx / ga;
      if (au == 0.0) { ssmin = (fhmn * fhmx) / ga; ssmax = ga; }
      else {
        double as_ = 1.0 + fhmn / fhmx;
        double at  = (fhmx - fhmn) / fhmx;
        double t1 = as_ * au, t2 = at * au;
        double c = 1.0 / (sqrt(1.0 + t1 * t1) + sqrt(1.0 + t2 * t2));
        ssmin = (fhmn * c) * au; ssmin = ssmin + ssmin;
        ssmax = ga / (c + c);
      }
    }
  }
}

static __device__ void lasv2(double f, double g, double h,
                             double &ssmin, double &ssmax,
                             double &snr, double &csr, double &snl, double &csl) {
  double ft = f, fa = fabs(f), ht = h, ha = fabs(h);
  int pmax = 1;
  bool swp = (ha > fa);
  if (swp) { pmax = 3; double t = ft; ft = ht; ht = t; t = fa; fa = ha; ha = t; }
  double gt = g, ga = fabs(g);
  double clt = 0, crt = 0, slt = 0, srt = 0;
  if (ga == 0.0) {
    ssmin = ha; ssmax = fa;
    clt = 1.0; crt = 1.0; slt = 0.0; srt = 0.0;
  } else {
    bool gasmal = true;
    if (ga > fa) {
      pmax = 2;
      if ((fa / ga) < EPSV) {
        gasmal = false;
        ssmax = ga;
        if (ha > 1.0) ssmin = fa / (ga / ha);
        else          ssmin = (fa / ga) * ha;
        clt = 1.0; slt = ht / gt; srt = 1.0; crt = ft / gt;
      }
    }
    if (gasmal) {
      double dd = fa - ha, l;
      if (dd == fa) l = 1.0; else l = dd / fa;
      double mv = gt / ft;
      double t = 2.0 - l;
      double mm = mv * mv, tt = t * t;
      double s = sqrt(tt + mm);
      double r = (l == 0.0) ? fabs(mv) : sqrt(l * l + mm);
      double a = 0.5 * (s + r);
      ssmin = ha / a;
      ssmax = fa * a;
      if (mm == 0.0) {
        if (l == 0.0) t = copysign(2.0, ft) * copysign(1.0, gt);
        else          t = gt / copysign(dd, ft) + mv / t;
      } else {
        t = (mv / (s + t) + mv / (r + l)) * (1.0 + a);
      }
      double lq = sqrt(t * t + 4.0);
      crt = 2.0 / lq;
      srt = t / lq;
      clt = (crt + srt * mv) / a;
      slt = (ht / ft) * srt / a;
    }
  }
  if (swp) { csl = srt; snl = crt; csr = slt; snr = clt; }
  else     { csl = clt; snl = slt; csr = crt; snr = srt; }
  double tsign = 1.0;
  if (pmax == 1) tsign = copysign(1.0, csr) * copysign(1.0, csl) * copysign(1.0, f);
  if (pmax == 2) tsign = copysign(1.0, snr) * copysign(1.0, csl) * copysign(1.0, g);
  if (pmax == 3) tsign = copysign(1.0, snr) * copysign(1.0, snl) * copysign(1.0, h);
  ssmax = copysign(ssmax, tsign);
  ssmin = copysign(ssmin, tsign * copysign(1.0, f) * copysign(1.0, h));
}

static __device__ __forceinline__ void rot_rows(double vt[3][3], int lo, double c, double s) {
  if (c != 1.0 || s != 0.0) {
    for (int k = 0; k < 3; ++k) {
      double tp = vt[lo + 1][k];
      vt[lo + 1][k] = c * tp - s * vt[lo][k];
      vt[lo][k]     = s * tp + c * vt[lo][k];
    }
  }
}

static __device__ void bdsqr3(double d[3], double e[2], double vt[3][3]) {
  const double tol = TOLV;
  double sminoa = fabs(d[0]);
  if (sminoa != 0.0) {
    double mu = sminoa;
    mu = fabs(d[1]) * (mu / (mu + fabs(e[0])));
    sminoa = fmin(sminoa, mu);
    if (sminoa != 0.0) {
      mu = fabs(d[2]) * (mu / (mu + fabs(e[1])));
      sminoa = fmin(sminoa, mu);
    }
  }
  sminoa /= sqrt(3.0);
  double thresh = fmax(tol * sminoa, 54.0 * UNFLV);
  int m = 3, oldll = -1, oldm = -1, idir = 0;
  double sminl = 0.0;
  for (int guard = 0; guard < 500 && m > 1; ++guard) {
    double smax = fabs(d[m - 1]);
    int ll = 0;
    bool split = false;
    for (int lll = 1; lll <= m - 1; ++lll) {
      int l = m - lll;
      double abss = fabs(d[l - 1]);
      double abse = fabs(e[l - 1]);
      if (abse <= thresh) { ll = l; split = true; break; }
      smax = fmax(smax, fmax(abss, abse));
    }
    if (split) {
      e[ll - 1] = 0.0;
      if (ll == m - 1) { m = m - 1; continue; }
      ll = ll + 1;
    } else ll = 1;
    if (ll == m - 1) {
      double sigmn, sigmx, sinr, cosr, sinl, cosl;
      lasv2(d[m - 2], e[m - 2], d[m - 1], sigmn, sigmx, sinr, cosr, sinl, cosl);
      d[m - 2] = sigmx; e[m - 2] = 0.0; d[m - 1] = sigmn;
      for (int k = 0; k < 3; ++k) {
        double x = vt[m - 2][k], y = vt[m - 1][k];
        vt[m - 2][k] = cosr * x + sinr * y;
        vt[m - 1][k] = cosr * y - sinr * x;
      }
      m -= 2;
      continue;
    }
    if (ll > oldm || m < oldll)
      idir = (fabs(d[ll - 1]) >= fabs(d[m - 1])) ? 1 : 2;
    bool deflated = false;
    if (idir == 1) {
      if (fabs(e[m - 2]) <= tol * fabs(d[m - 1])) { e[m - 2] = 0.0; continue; }
      double mu = fabs(d[ll - 1]);
      sminl = mu;
      for (int lll = ll; lll <= m - 1; ++lll) {
        if (fabs(e[lll - 1]) <= tol * mu) { e[lll - 1] = 0.0; deflated = true; break; }
        mu = fabs(d[lll]) * (mu / (mu + fabs(e[lll - 1])));
        sminl = fmin(sminl, mu);
      }
    } else {
      if (fabs(e[ll - 1]) <= tol * fabs(d[ll - 1])) { e[ll - 1] = 0.0; continue; }
      double mu = fabs(d[m - 1]);
      sminl = mu;
      for (int lll = m - 1; lll >= ll; --lll) {
        if (fabs(e[lll - 1]) <= tol * mu) { e[lll - 1] = 0.0; deflated = true; break; }
        mu = fabs(d[lll - 1]) * (mu / (mu + fabs(e[lll - 1])));
        sminl = fmin(sminl, mu);
      }
    }
    if (deflated) continue;
    oldll = ll; oldm = m;
    double shift = 0.0, rdum = 0.0;
    if (!(3.0 * tol * (sminl / smax) <= fmax(EPSV, 0.01 * tol))) {
      double sll;
      if (idir == 1) { sll = fabs(d[ll - 1]); las2(d[m - 2], e[m - 2], d[m - 1], shift, rdum); }
      else           { sll = fabs(d[m - 1]); las2(d[ll - 1], e[ll - 1], d[ll], shift, rdum); }
      if (sll > 0.0 && (shift / sll) * (shift / sll) < EPSV) shift = 0.0;
    }
    double csv[2], snv[2];
    if (shift == 0.0) {
      if (idir == 1) {
        double cs = 1.0, oldcs = 1.0, sn = 0.0, oldsn = 0.0, r = 0.0;
        for (int i = ll; i <= m - 1; ++i) {
          lartg(d[i - 1] * cs, e[i - 1], cs, sn, r);
          if (i > ll) e[i - 2] = oldsn * r;
          lartg(oldcs * r, d[i] * sn, oldcs, oldsn, d[i - 1]);
          csv[i - ll] = cs; snv[i - ll] = sn;
        }
        double h = d[m - 1] * cs;
        d[m - 1] = h * oldcs;
        e[m - 2] = h * oldsn;
        for (int j = 0; j <= m - ll - 1; ++j) rot_rows(vt, ll - 1 + j, csv[j], snv[j]);
        if (fabs(e[m - 2]) <= thresh) e[m - 2] = 0.0;
      } else {
        double cs = 1.0, oldcs = 1.0, sn = 0.0, oldsn = 0.0, r = 0.0;
        for (int i = m; i >= ll + 1; --i) {
          lartg(d[i - 1] * cs, e[i - 2], cs, sn, r);
          if (i < m) e[i - 1] = oldsn * r;
          lartg(oldcs * r, d[i - 2] * sn, oldcs, oldsn, d[i - 1]);
          csv[i - ll - 1] = oldcs; snv[i - ll - 1] = -oldsn;
        }
        double h = d[ll - 1] * cs;
        d[ll - 1] = h * oldcs;
        e[ll - 1] = h * oldsn;
        for (int j = m - ll - 1; j >= 0; --j) rot_rows(vt, ll - 1 + j, csv[j], snv[j]);
        if (fabs(e[ll - 1]) <= thresh) e[ll - 1] = 0.0;
      }
    } else {
      if (idir == 1) {
        double f = (fabs(d[ll - 1]) - shift) * (copysign(1.0, d[ll - 1]) + shift / d[ll - 1]);
        double g = e[ll - 1], cosr, sinr, cosl, sinl, r;
        for (int i = ll; i <= m - 1; ++i) {
          lartg(f, g, cosr, sinr, r);
          if (i > ll) e[i - 2] = r;
          f = cosr * d[i - 1] + sinr * e[i - 1];
          e[i - 1] = cosr * e[i - 1] - sinr * d[i - 1];
          g = sinr * d[i];
          d[i] = cosr * d[i];
          lartg(f, g, cosl, sinl, r);
          d[i - 1] = r;
          f = cosl * e[i - 1] + sinl * d[i];
          d[i] = cosl * d[i] - sinl * e[i - 1];
          if (i < m - 1) { g = sinl * e[i]; e[i] = cosl * e[i]; }
          csv[i - ll] = cosr; snv[i - ll] = sinr;
        }
        e[m - 2] = f;
        for (int j = 0; j <= m - ll - 1; ++j) rot_rows(vt, ll - 1 + j, csv[j], snv[j]);
        if (fabs(e[m - 2]) <= thresh) e[m - 2] = 0.0;
      } else {
        double f = (fabs(d[m - 1]) - shift) * (copysign(1.0, d[m - 1]) + shift / d[m - 1]);
        double g = e[m - 2], cosr, sinr, cosl, sinl, r;
        for (int i = m; i >= ll + 1; --i) {
          lartg(f, g, cosr, sinr, r);
          if (i < m) e[i - 1] = r;
          f = cosr * d[i - 1] + sinr * e[i - 2];
          e[i - 2] = cosr * e[i - 2] - sinr * d[i - 1];
          g = sinr * d[i - 2];
          d[i - 2] = cosr * d[i - 2];
          lartg(f, g, cosl, sinl, r);
          d[i - 1] = r;
          f = cosl * e[i - 2] + sinl * d[i - 2];
          d[i - 2] = cosl * d[i - 2] - sinl * e[i - 2];
          if (i > ll + 1) { g = sinl * e[i - 3]; e[i - 3] = cosl * e[i - 3]; }
          csv[i - ll - 1] = cosr; snv[i - ll - 1] = sinr;
        }
        e[ll - 1] = f;
        for (int j = m - ll - 1; j >= 0; --j) rot_rows(vt, ll - 1 + j, csv[j], snv[j]);
        if (fabs(e[ll - 1]) <= thresh) e[ll - 1] = 0.0;
      }
    }
  }
  for (int i = 0; i < 3; ++i)
    if (d[i] < 0.0) { d[i] = -d[i]; for (int k = 0; k < 3; ++k) vt[i][k] = -vt[i][k]; }
}

static __device__ void lapack_normal(double A[KK][3], double &nx, double &ny, double &nz) {
#pragma unroll
  for (int i = 0; i < 3; ++i) {
    double ss = 0.0;
#pragma unroll
    for (int j = i + 1; j < KK; ++j) ss += A[j][i] * A[j][i];
    double xnorm = sqrt(ss);
    if (xnorm != 0.0) {
      double alpha = A[i][i];
      double beta = -copysign(lapy2d(alpha, xnorm), alpha);
      double tau = (beta - alpha) / beta;
      double sc = 1.0 / (alpha - beta);
#pragma unroll
      for (int j = i + 1; j < KK; ++j) A[j][i] *= sc;
      A[i][i] = beta;
#pragma unroll
      for (int c = i + 1; c < 3; ++c) {
        double w = A[i][c];
#pragma unroll
        for (int j = i + 1; j < KK; ++j) w += A[j][i] * A[j][c];
        w *= tau;
        A[i][c] -= w;
#pragma unroll
        for (int j = i + 1; j < KK; ++j) A[j][c] -= w * A[j][i];
      }
    }
  }
  double r11 = A[0][0], r12 = A[0][1], r13 = A[0][2];
  double r22 = A[1][1], r23 = A[1][2], r33 = A[2][2];
  double d[3], e[2];
  double taup1 = 0.0, v3 = 0.0;
  d[0] = r11;
  double a22 = r22, a23 = r23, a32 = 0.0, a33 = r33;
  if (r13 != 0.0) {
    double betap = -copysign(lapy2d(r12, r13), r12);
    taup1 = (betap - r12) / betap;
    v3 = r13 / (r12 - betap);
    e[0] = betap;
    double w2 = (a22 + a23 * v3) * taup1;
    a22 -= w2; a23 -= w2 * v3;
    double w3 = (a33 * v3) * taup1;
    a32 = -w3; a33 -= w3 * v3;
  } else {
    e[0] = r12;
  }
  if (a32 != 0.0) {
    double beta2 = -copysign(lapy2d(a22, a32), a22);
    double tq = (beta2 - a22) / beta2;
    double v2 = a32 / (a22 - beta2);
    d[1] = beta2;
    double w = (a23 + v2 * a33) * tq;
    a23 -= w; a33 -= w * v2;
  } else d[1] = a22;
  e[1] = a23;
  d[2] = a33;
  double vt[3][3] = {{1,0,0},{0,1,0},{0,0,1}};
  bdsqr3(d, e, vt);
  int im = 0;
  if (d[1] < d[im]) im = 1;
  if (d[2] < d[im]) im = 2;
  double w1 = vt[im][0], w2 = vt[im][1], w3 = vt[im][2];
  double sdot = (w2 + w3 * v3) * taup1;
  w2 -= sdot; w3 -= sdot * v3;
  double inv = 1.0 / sqrt(w1 * w1 + w2 * w2 + w3 * w3);
  nx = w1 * inv; ny = w2 * inv; nz = w3 * inv;
}

// ---------------- Kernel 1: s-space probe-bound two-pass KNN (16 lanes/point) ----------------
// s = dot(p, q) - 0.5|q|^2  is monotone-DECREASING in dd = |p|^2 - 2s.
// Top-10 smallest dd == top-10 largest s. Probe with max-accs; collect s >= thr.
#define INS2(Kp) { bool lt_ = x < Kp; unsigned long long old_ = Kp; Kp = lt_ ? x : Kp; x = lt_ ? old_ : x; }
#define CSWAPU(U,V) { if (V < U) { unsigned long long t_ = U; U = V; V = t_; } }
#define CSWAPFD(U,V) { float mx_ = fmaxf(U, V); V = fminf(U, V); U = mx_; }   // descending

// pinned score: identical instruction sequence everywhere (qw = -0.5*|q|^2)
static __device__ __forceinline__ float score_s(float qx, float qy, float qz, float qw,
                                                float xi, float yi, float zi) {
  return fmaf(xi, qx, fmaf(yi, qy, fmaf(zi, qz, qw)));
}
static __device__ __forceinline__ float sqnorm(float x, float y, float z) {
  return __fadd_rn(__fadd_rn(__fmul_rn(x, x), __fmul_rn(y, y)), __fmul_rn(z, z));
}
// key: ascending-u64 order == (s descending, idx ascending) == top_k order
static __device__ __forceinline__ unsigned long long s_key(float s, int idx) {
  unsigned u = __float_as_uint(s);
  u = (u & 0x80000000u) ? ~u : (u | 0x80000000u);   // monotone increasing in s
  return ((unsigned long long)(~u) << 32) | (unsigned)idx;
}

__global__ __launch_bounds__(TPB, 1)
void lfl_knn(const float* __restrict__ xyz1, int* __restrict__ idxbuf) {
  __shared__ float4 tile[TILE];                       // 8 KB
  __shared__ unsigned long long gbuf[PPB][CAP];       // 6 KB
  __shared__ unsigned int gcnt[PPB];
  const int t    = threadIdx.x;
  const int b    = blockIdx.x / BPBK;
  const int pb   = blockIdx.x % BPBK;
  const int g    = t >> 4;         // point group within block (0..15)
  const int sub  = t & 15;         // lane within group
  const int i    = pb * PPB + g;
  const float* base = xyz1 + (size_t)b * NN * 3;

  const float xi = base[3 * i], yi = base[3 * i + 1], zi = base[3 * i + 2];

  // ---- pass 1: 8 independent max-accumulators per lane (1 fmaxf/candidate) ----
  float b0 = -INFINITY, b1 = -INFINITY, b2 = -INFINITY, b3 = -INFINITY,
        b4 = -INFINITY, b5 = -INFINITY, b6 = -INFINITY, b7 = -INFINITY;

  for (int t0 = 0; t0 < NN; t0 += TILE) {
    for (int p = t; p < TILE; p += TPB) {
      int j = t0 + p;
      float x = base[3 * j], y = base[3 * j + 1], z = base[3 * j + 2];
      tile[p] = make_float4(x, y, z, __fmul_rn(-0.5f, sqnorm(x, y, z)));
    }
    __syncthreads();
    for (int k = 0; k < TILE / GPP; k += 8) {
      float4 q0 = tile[sub + (k + 0) * GPP];
      float4 q1 = tile[sub + (k + 1) * GPP];
      float4 q2 = tile[sub + (k + 2) * GPP];
      float4 q3 = tile[sub + (k + 3) * GPP];
      float4 q4 = tile[sub + (k + 4) * GPP];
      float4 q5 = tile[sub + (k + 5) * GPP];
      float4 q6 = tile[sub + (k + 6) * GPP];
      float4 q7 = tile[sub + (k + 7) * GPP];
      b0 = fmaxf(b0, score_s(q0.x, q0.y, q0.z, q0.w, xi, yi, zi));
      b1 = fmaxf(b1, score_s(q1.x, q1.y, q1.z, q1.w, xi, yi, zi));
      b2 = fmaxf(b2, score_s(q2.x, q2.y, q2.z, q2.w, xi, yi, zi));
      b3 = fmaxf(b3, score_s(q3.x, q3.y, q3.z, q3.w, xi, yi, zi));
      b4 = fmaxf(b4, score_s(q4.x, q4.y, q4.z, q4.w, xi, yi, zi));
      b5 = fmaxf(b5, score_s(q5.x, q5.y, q5.z, q5.w, xi, yi, zi));
      b6 = fmaxf(b6, score_s(q6.x, q6.y, q6.z, q6.w, xi, yi, zi));
      b7 = fmaxf(b7, score_s(q7.x, q7.y, q7.z, q7.w, xi, yi, zi));
    }
    __syncthreads();
  }
  // descending Batcher-8 sort (19 compares), once per point
  CSWAPFD(b0, b1) CSWAPFD(b2, b3) CSWAPFD(b4, b5) CSWAPFD(b6, b7)
  CSWAPFD(b0, b2) CSWAPFD(b1, b3) CSWAPFD(b4, b6) CSWAPFD(b5, b7)
  CSWAPFD(b1, b2) CSWAPFD(b5, b6)
  CSWAPFD(b0, b4) CSWAPFD(b1, b5) CSWAPFD(b2, b6) CSWAPFD(b3, b7)
  CSWAPFD(b2, b4) CSWAPFD(b3, b5)
  CSWAPFD(b1, b2) CSWAPFD(b3, b4) CSWAPFD(b5, b6)

  // ---- dup-agnostic pop-merge (max) over 128-value union: thr <= true 10th-largest s ----
  float thr;
  {
    float m = b0;
#pragma unroll
    for (int r = 0; r < KK; ++r) {
      m = b0;
      m = fmaxf(m, __shfl_xor(m, 1));
      m = fmaxf(m, __shfl_xor(m, 2));
      m = fmaxf(m, __shfl_xor(m, 4));
      m = fmaxf(m, __shfl_xor(m, 8));
      if (b0 == m) { b0 = b1; b1 = b2; b2 = b3; b3 = b4; b4 = b5; b5 = b6; b6 = b7; b7 = -INFINITY; }
    }
    thr = m;   // dup lanes pop together: bound only falls -> still a valid (wider) bound
  }

  // ---- pass 2: collect all s >= thr ----
  if (sub == 0) gcnt[g] = 0;
  __syncthreads();

  for (int t0 = 0; t0 < NN; t0 += TILE) {
    for (int p = t; p < TILE; p += TPB) {
      int j = t0 + p;
      float x = base[3 * j], y = base[3 * j + 1], z = base[3 * j + 2];
      tile[p] = make_float4(x, y, z, __fmul_rn(-0.5f, sqnorm(x, y, z)));
    }
    __syncthreads();
#pragma unroll 8
    for (int c = sub; c < TILE; c += GPP) {
      float4 q = tile[c];
      float s = score_s(q.x, q.y, q.z, q.w, xi, yi, zi);
      if (s >= thr) {
        unsigned long long key = s_key(s, t0 + c);
        unsigned pos = atomicAdd(&gcnt[g], 1u);
        if (pos < (unsigned)CAP) gbuf[g][pos] = key;
      }
    }
    __syncthreads();
  }

  const unsigned cnt = gcnt[g];
  const int gid = b * NN + i;

  if (cnt <= (unsigned)CAP) {
    // ---- sort <=48 keys with 16 lanes (3-deep sorted per lane + pop-merge) ----
    unsigned long long e0 = (sub      < (int)cnt) ? gbuf[g][sub]      : ~0ULL;
    unsigned long long e1 = (sub + 16 < (int)cnt) ? gbuf[g][sub + 16] : ~0ULL;
    unsigned long long e2 = (sub + 32 < (int)cnt) ? gbuf[g][sub + 32] : ~0ULL;
    CSWAPU(e0, e1) CSWAPU(e1, e2) CSWAPU(e0, e1)
#pragma unroll
    for (int r = 0; r < KK; ++r) {
      unsigned long long m = e0, o;
      o = __shfl_xor(m, 1); m = (o < m) ? o : m;
      o = __shfl_xor(m, 2); m = (o < m) ? o : m;
      o = __shfl_xor(m, 4); m = (o < m) ? o : m;
      o = __shfl_xor(m, 8); m = (o < m) ? o : m;
      if (e0 == m) { e0 = e1; e1 = e2; e2 = ~0ULL; }  // keys unique -> exactly one lane pops
      if (sub == (r & 15)) idxbuf[gid * KK + r] = (int)(unsigned)(m & 0xFFFFFFFFULL);
    }
  } else {
    // ---- exact fallback (essentially never): per-lane u64 top-10 over global ----
    unsigned long long k0 = ~0ULL, k1 = ~0ULL, k2 = ~0ULL, k3 = ~0ULL, k4 = ~0ULL,
                       k5 = ~0ULL, k6 = ~0ULL, k7 = ~0ULL, k8 = ~0ULL, k9 = ~0ULL;
    for (int c = sub; c < NN; c += GPP) {
      float x = base[3 * c], y = base[3 * c + 1], z = base[3 * c + 2];
      float s = score_s(x, y, z, __fmul_rn(-0.5f, sqnorm(x, y, z)), xi, yi, zi);
      unsigned long long key = s_key(s, c);
      if (key < k9) {
        unsigned long long x2 = key;
        { unsigned long long &x = x2;
          INS2(k0) INS2(k1) INS2(k2) INS2(k3) INS2(k4)
          INS2(k5) INS2(k6) INS2(k7) INS2(k8) INS2(k9) }
      }
    }
#pragma unroll
    for (int r = 0; r < KK; ++r) {
      unsigned long long m = k0, o;
      o = __shfl_xor(m, 1); m = (o < m) ? o : m;
      o = __shfl_xor(m, 2); m = (o < m) ? o : m;
      o = __shfl_xor(m, 4); m = (o < m) ? o : m;
      o = __shfl_xor(m, 8); m = (o < m) ? o : m;
      if (k0 == m) { k0=k1;k1=k2;k2=k3;k3=k4;k4=k5;k5=k6;k6=k7;k7=k8;k8=k9;k9=~0ULL; }
      if (sub == (r & 15)) idxbuf[gid * KK + r] = (int)(unsigned)(m & 0xFFFFFFFFULL);
    }
  }
}

// ---------------- Kernel 2: split-cloud SVD — 1 SVD per thread ----------------
__global__ __launch_bounds__(TPB, 1)
void lfl_svd(const float* __restrict__ xyz1, const float* __restrict__ xyz2,
             const int* __restrict__ idxbuf, double* __restrict__ partials) {
  __shared__ double pv[TPB];
  __shared__ double red1[128], red2[128];
  const int t = threadIdx.x;
  const int half = t >> 7;          // 0: cloud1, 1: cloud2
  const int lt = t & 127;
  const int pid = blockIdx.x * 128 + lt;   // point id 0..NPTS-1
  const int b = pid / NN, i = pid % NN;
  const float* basep = (half == 0) ? (xyz1 + (size_t)b * NN * 3)
                                   : (xyz2 + (size_t)b * NN * 3);
  double p;
  {
    double A[KK][3];
    double cx = 0, cy = 0, cz = 0;
#pragma unroll
    for (int s = 0; s < KK; ++s) {
      int j = idxbuf[pid * KK + s];
      j = ((unsigned)j < (unsigned)NN) ? j : 0;   // defensive: fault -> numeric miss
      A[s][0] = (double)basep[3 * j];
      A[s][1] = (double)basep[3 * j + 1];
      A[s][2] = (double)basep[3 * j + 2];
      cx += A[s][0]; cy += A[s][1]; cz += A[s][2];
    }
    cx *= 0.1; cy *= 0.1; cz *= 0.1;
#pragma unroll
    for (int s = 0; s < KK; ++s) { A[s][0] -= cx; A[s][1] -= cy; A[s][2] -= cz; }
    double nx, ny, nz;
    lapack_normal(A, nx, ny, nz);
    p = ((double)basep[3 * i] - cx) * nx + ((double)basep[3 * i + 1] - cy) * ny +
        ((double)basep[3 * i + 2] - cz) * nz;
  }
  pv[t] = p;
  __syncthreads();

  if (t < 128) {
    double p1 = pv[t], p2 = pv[t + 128];
    double da = fabs(p1) - fabs(p2);
    double df = p2 - p1;
    double bent = df > 0.0 ? df : 0.0;
    red1[t] = da * da;
    red2[t] = bent * bent;
  }
  __syncthreads();
  for (int s = 64; s > 0; s >>= 1) {
    if (t < s) { red1[t] += red1[t + s]; red2[t] += red2[t + s]; }
    __syncthreads();
  }
  if (t == 0) {
    partials[2 * blockIdx.x]     = red1[0];
    partials[2 * blockIdx.x + 1] = red2[0];
  }
}

// ---------------- Kernel 3: parallel deterministic finalize ----------------
__global__ __launch_bounds__(TPB)
void lfl_final(const double* __restrict__ partials, float* __restrict__ out) {
  __shared__ double r1[TPB], r2[TPB];
  const int t = threadIdx.x;
  r1[t] = partials[2 * t];
  r2[t] = partials[2 * t + 1];
  __syncthreads();
  for (int s = TPB / 2; s > 0; s >>= 1) {
    if (t < s) { r1[t] += r1[t + s]; r2[t] += r2[t + s]; }
    __syncthreads();
  }
  if (t == 0) out[0] = (float)((r1[0] + 5.0 * r2[0]) / (double)NPTS);
}

extern "C" void kernel_launch(void* const* d_in, const int* in_sizes, int n_in,
                              void* d_out, int out_size, void* d_ws, size_t ws_size,
                              hipStream_t stream) {
  const float* xyz1 = (const float*)d_in[0];
  const float* xyz2 = (const float*)d_in[1];
  float* out = (float*)d_out;
  double* partials = (double*)d_ws;                      // 4 KB
  int* idxbuf = (int*)((char*)d_ws + 4096);              // 1.31 MB

  lfl_knn<<<KNBLK, TPB, 0, stream>>>(xyz1, idxbuf);
  lfl_svd<<<SVDBLK, TPB, 0, stream>>>(xyz1, xyz2, idxbuf, partials);
  lfl_final<<<1, TPB, 0, stream>>>(partials, out);
}

// Round 16
// 98.514 us; speedup vs baseline: 1.2840x; 1.0464x over previous
//
#include <hip/hip_runtime.h>
#include <math.h>

#define BB   8
#define NN   4096
#define KK   10
#define TPB  256
#define NPTS (BB * NN)      // 32768

// KNN decomposition: 16 lanes per point, 16 points per block (R12 structure)
#define GPP  16
#define PPB  (TPB / GPP)            // 16
#define BPBK (NN / PPB)             // 256 blocks per batch
#define KNBLK (BB * BPBK)           // 2048 blocks
#define TILE 512
#define PROBE (NN / 2)              // R16: probe subset (valid bound from any subset)
#define CAP  64                     // pass-2 buffer slots per group

// SVD-side: 256 blocks, each covers 128 points x {cloud1, cloud2}
#define SVDBLK 256
#define SBLK   256                  // partials entries

// --- LAPACK environment constants (reference = numpy float32 sgesdd) ---
#define LARTG_OLD 0
#define EPSV  5.9604644775390625e-8    // 2^-24
#define UNFLV 1.1754943508222875e-38   // 2^-126
#define TOLV (10.0 * EPSV)

static __device__ __forceinline__ double lapy2d(double x, double y) {
  double xa = fabs(x), ya = fabs(y);
  double w = fmax(xa, ya), z = fmin(xa, ya);
  if (z == 0.0) return w;
  double q = z / w;
  return w * sqrt(1.0 + q * q);
}

static __device__ __forceinline__ void lartg(double f, double g,
                                             double &c, double &s, double &r) {
#if LARTG_OLD
  if (g == 0.0) { c = 1.0; s = 0.0; r = f; }
  else if (f == 0.0) { c = 0.0; s = 1.0; r = g; }
  else {
    double d = sqrt(f * f + g * g);
    c = f / d; s = g / d; r = d;
    if (fabs(f) > fabs(g) && c < 0.0) { c = -c; s = -s; r = -r; }
  }
#else
  if (g == 0.0) { c = 1.0; s = 0.0; r = f; }
  else if (f == 0.0) { c = 0.0; s = copysign(1.0, g); r = fabs(g); }
  else {
    double d = sqrt(f * f + g * g);
    c = fabs(f) / d;
    r = copysign(d, f);
    s = g / r;
  }
#endif
}

static __device__ void las2(double f, double g, double h, double &ssmin, double &ssmax) {
  double fa = fabs(f), ga = fabs(g), ha = fabs(h);
  double fhmn = fmin(fa, ha), fhmx = fmax(fa, ha);
  if (fhmn == 0.0) {
    ssmin = 0.0;
    if (fhmx == 0.0) ssmax = ga;
    else {
      double mn = fmin(fhmx, ga), mx = fmax(fhmx, ga);
      double rr = mn / mx;
      ssmax = mx * sqrt(1.0 + rr * rr);
    }
  } else {
    if (ga < fhmx) {
      double as_ = 1.0 + fhmn / fhmx;
      double at  = (fhmx - fhmn) / fhmx;
      double au  = (ga / fhmx); au = au * au;
      double c   = 2.0 / (sqrt(as_ * as_ + au) + sqrt(at * at + au));
      ssmin = fhmn * c;
      ssmax = fhmx / c;
    } else {
      double au = fhmx / ga;
      if (au == 0.0) { ssmin = (fhmn * fhmx) / ga; ssmax = ga; }
      else {
        double as_ = 1.0 + fhmn / fhmx;
        double at  = (fhmx - fhmn) / fhmx;
        double t1 = as_ * au, t2 = at * au;
        double c = 1.0 / (sqrt(1.0 + t1 * t1) + sqrt(1.0 + t2 * t2));
        ssmin = (fhmn * c) * au; ssmin = ssmin + ssmin;
        ssmax = ga / (c + c);
      }
    }
  }
}

static __device__ void lasv2(double f, double g, double h,
                             double &ssmin, double &ssmax,
                             double &snr, double &csr, double &snl, double &csl) {
  double ft = f, fa = fabs(f), ht = h, ha = fabs(h);
  int pmax = 1;
  bool swp = (ha > fa);
  if (swp) { pmax = 3; double t = ft; ft = ht; ht = t; t = fa; fa = ha; ha = t; }
  double gt = g, ga = fabs(g);
  double clt = 0, crt = 0, slt = 0, srt = 0;
  if (ga == 0.0) {
    ssmin = ha; ssmax = fa;
    clt = 1.0; crt = 1.0; slt = 0.0; srt = 0.0;
  } else {
    bool gasmal = true;
    if (ga > fa) {
      pmax = 2;
      if ((fa / ga) < EPSV) {
        gasmal = false;
        ssmax = ga;
        if (ha > 1.0) ssmin = fa / (ga / ha);
        else          ssmin = (fa / ga) * ha;
        clt = 1.0; slt = ht / gt; srt = 1.0; crt = ft / gt;
      }
    }
    if (gasmal) {
      double dd = fa - ha, l;
      if (dd == fa) l = 1.0; else l = dd / fa;
      double mv = gt / ft;
      double t = 2.0 - l;
      double mm = mv * mv, tt = t * t;
      double s = sqrt(tt + mm);
      double r = (l == 0.0) ? fabs(mv) : sqrt(l * l + mm);
      double a = 0.5 * (s + r);
      ssmin = ha / a;
      ssmax = fa * a;
      if (mm == 0.0) {
        if (l == 0.0) t = copysign(2.0, ft) * copysign(1.0, gt);
        else          t = gt / copysign(dd, ft) + mv / t;
      } else {
        t = (mv / (s + t) + mv / (r + l)) * (1.0 + a);
      }
      double lq = sqrt(t * t + 4.0);
      crt = 2.0 / lq;
      srt = t / lq;
      clt = (crt + srt * mv) / a;
      slt = (ht / ft) * srt / a;
    }
  }
  if (swp) { csl = srt; snl = crt; csr = slt; snr = clt; }
  else     { csl = clt; snl = slt; csr = crt; snr = srt; }
  double tsign = 1.0;
  if (pmax == 1) tsign = copysign(1.0, csr) * copysign(1.0, csl) * copysign(1.0, f);
  if (pmax == 2) tsign = copysign(1.0, snr) * copysign(1.0, csl) * copysign(1.0, g);
  if (pmax == 3) tsign = copysign(1.0, snr) * copysign(1.0, snl) * copysign(1.0, h);
  ssmax = copysign(ssmax, tsign);
  ssmin = copysign(ssmin, tsign * copysign(1.0, f) * copysign(1.0, h));
}

static __device__ __forceinline__ void rot_rows(double vt[3][3], int lo, double c, double s) {
  if (c != 1.0 || s != 0.0) {
    for (int k = 0; k < 3; ++k) {
      double tp = vt[lo + 1][k];
      vt[lo + 1][k] = c * tp - s * vt[lo][k];
      vt[lo][k]     = s * tp + c * vt[lo][k];
    }
  }
}

static __device__ void bdsqr3(double d[3], double e[2], double vt[3][3]) {
  const double tol = TOLV;
  double sminoa = fabs(d[0]);
  if (sminoa != 0.0) {
    double mu = sminoa;
    mu = fabs(d[1]) * (mu / (mu + fabs(e[0])));
    sminoa = fmin(sminoa, mu);
    if (sminoa != 0.0) {
      mu = fabs(d[2]) * (mu / (mu + fabs(e[1])));
      sminoa = fmin(sminoa, mu);
    }
  }
  sminoa /= sqrt(3.0);
  double thresh = fmax(tol * sminoa, 54.0 * UNFLV);
  int m = 3, oldll = -1, oldm = -1, idir = 0;
  double sminl = 0.0;
  for (int guard = 0; guard < 500 && m > 1; ++guard) {
    double smax = fabs(d[m - 1]);
    int ll = 0;
    bool split = false;
    for (int lll = 1; lll <= m - 1; ++lll) {
      int l = m - lll;
      double abss = fabs(d[l - 1]);
      double abse = fabs(e[l - 1]);
      if (abse <= thresh) { ll = l; split = true; break; }
      smax = fmax(smax, fmax(abss, abse));
    }
    if (split) {
      e[ll - 1] = 0.0;
      if (ll == m - 1) { m = m - 1; continue; }
      ll = ll + 1;
    } else ll = 1;
    if (ll == m - 1) {
      double sigmn, sigmx, sinr, cosr, sinl, cosl;
      lasv2(d[m - 2], e[m - 2], d[m - 1], sigmn, sigmx, sinr, cosr, sinl, cosl);
      d[m - 2] = sigmx; e[m - 2] = 0.0; d[m - 1] = sigmn;
      for (int k = 0; k < 3; ++k) {
        double x = vt[m - 2][k], y = vt[m - 1][k];
        vt[m - 2][k] = cosr * x + sinr * y;
        vt[m - 1][k] = cosr * y - sinr * x;
      }
      m -= 2;
      continue;
    }
    if (ll > oldm || m < oldll)
      idir = (fabs(d[ll - 1]) >= fabs(d[m - 1])) ? 1 : 2;
    bool deflated = false;
    if (idir == 1) {
      if (fabs(e[m - 2]) <= tol * fabs(d[m - 1])) { e[m - 2] = 0.0; continue; }
      double mu = fabs(d[ll - 1]);
      sminl = mu;
      for (int lll = ll; lll <= m - 1; ++lll) {
        if (fabs(e[lll - 1]) <= tol * mu) { e[lll - 1] = 0.0; deflated = true; break; }
        mu = fabs(d[lll]) * (mu / (mu + fabs(e[lll - 1])));
        sminl = fmin(sminl, mu);
      }
    } else {
      if (fabs(e[ll - 1]) <= tol * fabs(d[ll - 1])) { e[ll - 1] = 0.0; continue; }
      double mu = fabs(d[m - 1]);
      sminl = mu;
      for (int lll = m - 1; lll >= ll; --lll) {
        if (fabs(e[lll - 1]) <= tol * mu) { e[lll - 1] = 0.0; deflated = true; break; }
        mu = fabs(d[lll - 1]) * (mu / (mu + fabs(e[lll - 1])));
        sminl = fmin(sminl, mu);
      }
    }
    if (deflated) continue;
    oldll = ll; oldm = m;
    double shift = 0.0, rdum = 0.0;
    if (!(3.0 * tol * (sminl / smax) <= fmax(EPSV, 0.01 * tol))) {
      double sll;
      if (idir == 1) { sll = fabs(d[ll - 1]); las2(d[m - 2], e[m - 2], d[m - 1], shift, rdum); }
      else           { sll = fabs(d[m - 1]); las2(d[ll - 1], e[ll - 1], d[ll], shift, rdum); }
      if (sll > 0.0 && (shift / sll) * (shift / sll) < EPSV) shift = 0.0;
    }
    double csv[2], snv[2];
    if (shift == 0.0) {
      if (idir == 1) {
        double cs = 1.0, oldcs = 1.0, sn = 0.0, oldsn = 0.0, r = 0.0;
        for (int i = ll; i <= m - 1; ++i) {
          lartg(d[i - 1] * cs, e[i - 1], cs, sn, r);
          if (i > ll) e[i - 2] = oldsn * r;
          lartg(oldcs * r, d[i] * sn, oldcs, oldsn, d[i - 1]);
          csv[i - ll] = cs; snv[i - ll] = sn;
        }
        double h = d[m - 1] * cs;
        d[m - 1] = h * oldcs;
        e[m - 2] = h * oldsn;
        for (int j = 0; j <= m - ll - 1; ++j) rot_rows(vt, ll - 1 + j, csv[j], snv[j]);
        if (fabs(e[m - 2]) <= thresh) e[m - 2] = 0.0;
      } else {
        double cs = 1.0, oldcs = 1.0, sn = 0.0, oldsn = 0.0, r = 0.0;
        for (int i = m; i >= ll + 1; --i) {
          lartg(d[i - 1] * cs, e[i - 2], cs, sn, r);
          if (i < m) e[i - 1] = oldsn * r;
          lartg(oldcs * r, d[i - 2] * sn, oldcs, oldsn, d[i - 1]);
          csv[i - ll - 1] = oldcs; snv[i - ll - 1] = -oldsn;
        }
        double h = d[ll - 1] * cs;
        d[ll - 1] = h * oldcs;
        e[ll - 1] = h * oldsn;
        for (int j = m - ll - 1; j >= 0; --j) rot_rows(vt, ll - 1 + j, csv[j], snv[j]);
        if (fabs(e[ll - 1]) <= thresh) e[ll - 1] = 0.0;
      }
    } else {
      if (idir == 1) {
        double f = (fabs(d[ll - 1]) - shift) * (copysign(1.0, d[ll - 1]) + shift / d[ll - 1]);
        double g = e[ll - 1], cosr, sinr, cosl, sinl, r;
        for (int i = ll; i <= m - 1; ++i) {
          lartg(f, g, cosr, sinr, r);
          if (i > ll) e[i - 2] = r;
          f = cosr * d[i - 1] + sinr * e[i - 1];
          e[i - 1] = cosr * e[i - 1] - sinr * d[i - 1];
          g = sinr * d[i];
          d[i] = cosr * d[i];
          lartg(f, g, cosl, sinl, r);
          d[i - 1] = r;
          f = cosl * e[i - 1] + sinl * d[i];
          d[i] = cosl * d[i] - sinl * e[i - 1];
          if (i < m - 1) { g = sinl * e[i]; e[i] = cosl * e[i]; }
          csv[i - ll] = cosr; snv[i - ll] = sinr;
        }
        e[m - 2] = f;
        for (int j = 0; j <= m - ll - 1; ++j) rot_rows(vt, ll - 1 + j, csv[j], snv[j]);
        if (fabs(e[m - 2]) <= thresh) e[m - 2] = 0.0;
      } else {
        double f = (fabs(d[m - 1]) - shift) * (copysign(1.0, d[m - 1]) + shift / d[m - 1]);
        double g = e[m - 2], cosr, sinr, cosl, sinl, r;
        for (int i = m; i >= ll + 1; --i) {
          lartg(f, g, cosr, sinr, r);
          if (i < m) e[i - 1] = r;
          f = cosr * d[i - 1] + sinr * e[i - 2];
          e[i - 2] = cosr * e[i - 2] - sinr * d[i - 1];
          g = sinr * d[i - 2];
          d[i - 2] = cosr * d[i - 2];
          lartg(f, g, cosl, sinl, r);
          d[i - 1] = r;
          f = cosl * e[i - 2] + sinl * d[i - 2];
          d[i - 2] = cosl * d[i - 2] - sinl * e[i - 2];
          if (i > ll + 1) { g = sinl * e[i - 3]; e[i - 3] = cosl * e[i - 3]; }
          csv[i - ll - 1] = cosr; snv[i - ll - 1] = sinr;
        }
        e[ll - 1] = f;
        for (int j = m - ll - 1; j >= 0; --j) rot_rows(vt, ll - 1 + j, csv[j], snv[j]);
        if (fabs(e[ll - 1]) <= thresh) e[ll - 1] = 0.0;
      }
    }
  }
  for (int i = 0; i < 3; ++i)
    if (d[i] < 0.0) { d[i] = -d[i]; for (int k = 0; k < 3; ++k) vt[i][k] = -vt[i][k]; }
}

static __device__ void lapack_normal(double A[KK][3], double &nx, double &ny, double &nz) {
#pragma unroll
  for (int i = 0; i < 3; ++i) {
    double ss = 0.0;
#pragma unroll
    for (int j = i + 1; j < KK; ++j) ss += A[j][i] * A[j][i];
    double xnorm = sqrt(ss);
    if (xnorm != 0.0) {
      double alpha = A[i][i];
      double beta = -copysign(lapy2d(alpha, xnorm), alpha);
      double tau = (beta - alpha) / beta;
      double sc = 1.0 / (alpha - beta);
#pragma unroll
      for (int j = i + 1; j < KK; ++j) A[j][i] *= sc;
      A[i][i] = beta;
#pragma unroll
      for (int c = i + 1; c < 3; ++c) {
        double w = A[i][c];
#pragma unroll
        for (int j = i + 1; j < KK; ++j) w += A[j][i] * A[j][c];
        w *= tau;
        A[i][c] -= w;
#pragma unroll
        for (int j = i + 1; j < KK; ++j) A[j][c] -= w * A[j][i];
      }
    }
  }
  double r11 = A[0][0], r12 = A[0][1], r13 = A[0][2];
  double r22 = A[1][1], r23 = A[1][2], r33 = A[2][2];
  double d[3], e[2];
  double taup1 = 0.0, v3 = 0.0;
  d[0] = r11;
  double a22 = r22, a23 = r23, a32 = 0.0, a33 = r33;
  if (r13 != 0.0) {
    double betap = -copysign(lapy2d(r12, r13), r12);
    taup1 = (betap - r12) / betap;
    v3 = r13 / (r12 - betap);
    e[0] = betap;
    double w2 = (a22 + a23 * v3) * taup1;
    a22 -= w2; a23 -= w2 * v3;
    double w3 = (a33 * v3) * taup1;
    a32 = -w3; a33 -= w3 * v3;
  } else {
    e[0] = r12;
  }
  if (a32 != 0.0) {
    double beta2 = -copysign(lapy2d(a22, a32), a22);
    double tq = (beta2 - a22) / beta2;
    double v2 = a32 / (a22 - beta2);
    d[1] = beta2;
    double w = (a23 + v2 * a33) * tq;
    a23 -= w; a33 -= w * v2;
  } else d[1] = a22;
  e[1] = a23;
  d[2] = a33;
  double vt[3][3] = {{1,0,0},{0,1,0},{0,0,1}};
  bdsqr3(d, e, vt);
  int im = 0;
  if (d[1] < d[im]) im = 1;
  if (d[2] < d[im]) im = 2;
  double w1 = vt[im][0], w2 = vt[im][1], w3 = vt[im][2];
  double sdot = (w2 + w3 * v3) * taup1;
  w2 -= sdot; w3 -= sdot * v3;
  double inv = 1.0 / sqrt(w1 * w1 + w2 * w2 + w3 * w3);
  nx = w1 * inv; ny = w2 * inv; nz = w3 * inv;
}

// ---------------- Kernel 1: subset-probe s-space two-pass KNN (16 lanes/point) ----------------
// s = dot(p, q) - 0.5|q|^2  is monotone-DECREASING in dd.  Top-10 smallest dd ==
// top-10 largest s.  Pass 1 probes only PROBE candidates: the (dup-agnostic,
// union-widened) 10th-largest of ANY SUBSET is <= true s10, so thr is a valid
// bound; pass 2 over ALL candidates + exact sort restores exact top_k.
#define INS2(Kp) { bool lt_ = x < Kp; unsigned long long old_ = Kp; Kp = lt_ ? x : Kp; x = lt_ ? old_ : x; }
#define CSWAPU(U,V) { if (V < U) { unsigned long long t_ = U; U = V; V = t_; } }
#define CSWAPFD(U,V) { float mx_ = fmaxf(U, V); V = fminf(U, V); U = mx_; }   // descending

// pinned score: identical instruction sequence everywhere (qw = -0.5*|q|^2)
static __device__ __forceinline__ float score_s(float qx, float qy, float qz, float qw,
                                                float xi, float yi, float zi) {
  return fmaf(xi, qx, fmaf(yi, qy, fmaf(zi, qz, qw)));
}
static __device__ __forceinline__ float sqnorm(float x, float y, float z) {
  return __fadd_rn(__fadd_rn(__fmul_rn(x, x), __fmul_rn(y, y)), __fmul_rn(z, z));
}
// key: ascending-u64 order == (s descending, idx ascending) == top_k order
static __device__ __forceinline__ unsigned long long s_key(float s, int idx) {
  unsigned u = __float_as_uint(s);
  u = (u & 0x80000000u) ? ~u : (u | 0x80000000u);   // monotone increasing in s
  return ((unsigned long long)(~u) << 32) | (unsigned)idx;
}

__global__ __launch_bounds__(TPB, 1)
void lfl_knn(const float* __restrict__ xyz1, int* __restrict__ idxbuf) {
  __shared__ float4 tile[TILE];                       // 8 KB
  __shared__ unsigned long long gbuf[PPB][CAP];       // 8 KB
  __shared__ unsigned int gcnt[PPB];
  const int t    = threadIdx.x;
  const int b    = blockIdx.x / BPBK;
  const int pb   = blockIdx.x % BPBK;
  const int g    = t >> 4;         // point group within block (0..15)
  const int sub  = t & 15;         // lane within group
  const int i    = pb * PPB + g;
  const float* base = xyz1 + (size_t)b * NN * 3;

  const float xi = base[3 * i], yi = base[3 * i + 1], zi = base[3 * i + 2];

  // ---- pass 1 (subset probe): 8 independent max-accumulators per lane ----
  float b0 = -INFINITY, b1 = -INFINITY, b2 = -INFINITY, b3 = -INFINITY,
        b4 = -INFINITY, b5 = -INFINITY, b6 = -INFINITY, b7 = -INFINITY;

  for (int t0 = 0; t0 < PROBE; t0 += TILE) {
    for (int p = t; p < TILE; p += TPB) {
      int j = t0 + p;
      float x = base[3 * j], y = base[3 * j + 1], z = base[3 * j + 2];
      tile[p] = make_float4(x, y, z, __fmul_rn(-0.5f, sqnorm(x, y, z)));
    }
    __syncthreads();
    for (int k = 0; k < TILE / GPP; k += 8) {
      float4 q0 = tile[sub + (k + 0) * GPP];
      float4 q1 = tile[sub + (k + 1) * GPP];
      float4 q2 = tile[sub + (k + 2) * GPP];
      float4 q3 = tile[sub + (k + 3) * GPP];
      float4 q4 = tile[sub + (k + 4) * GPP];
      float4 q5 = tile[sub + (k + 5) * GPP];
      float4 q6 = tile[sub + (k + 6) * GPP];
      float4 q7 = tile[sub + (k + 7) * GPP];
      b0 = fmaxf(b0, score_s(q0.x, q0.y, q0.z, q0.w, xi, yi, zi));
      b1 = fmaxf(b1, score_s(q1.x, q1.y, q1.z, q1.w, xi, yi, zi));
      b2 = fmaxf(b2, score_s(q2.x, q2.y, q2.z, q2.w, xi, yi, zi));
      b3 = fmaxf(b3, score_s(q3.x, q3.y, q3.z, q3.w, xi, yi, zi));
      b4 = fmaxf(b4, score_s(q4.x, q4.y, q4.z, q4.w, xi, yi, zi));
      b5 = fmaxf(b5, score_s(q5.x, q5.y, q5.z, q5.w, xi, yi, zi));
      b6 = fmaxf(b6, score_s(q6.x, q6.y, q6.z, q6.w, xi, yi, zi));
      b7 = fmaxf(b7, score_s(q7.x, q7.y, q7.z, q7.w, xi, yi, zi));
    }
    __syncthreads();
  }
  // descending Batcher-8 sort (19 compares), once per point
  CSWAPFD(b0, b1) CSWAPFD(b2, b3) CSWAPFD(b4, b5) CSWAPFD(b6, b7)
  CSWAPFD(b0, b2) CSWAPFD(b1, b3) CSWAPFD(b4, b6) CSWAPFD(b5, b7)
  CSWAPFD(b1, b2) CSWAPFD(b5, b6)
  CSWAPFD(b0, b4) CSWAPFD(b1, b5) CSWAPFD(b2, b6) CSWAPFD(b3, b7)
  CSWAPFD(b2, b4) CSWAPFD(b3, b5)
  CSWAPFD(b1, b2) CSWAPFD(b3, b4) CSWAPFD(b5, b6)

  // ---- dup-agnostic pop-merge (max): thr <= true 10th-largest s ----
  float thr;
  {
    float m = b0;
#pragma unroll
    for (int r = 0; r < KK; ++r) {
      m = b0;
      m = fmaxf(m, __shfl_xor(m, 1));
      m = fmaxf(m, __shfl_xor(m, 2));
      m = fmaxf(m, __shfl_xor(m, 4));
      m = fmaxf(m, __shfl_xor(m, 8));
      if (b0 == m) { b0 = b1; b1 = b2; b2 = b3; b3 = b4; b4 = b5; b5 = b6; b6 = b7; b7 = -INFINITY; }
    }
    thr = m;   // subset + dup-pops only lower thr -> still a valid (wider) bound
  }

  // ---- pass 2: collect all s >= thr over the FULL candidate set ----
  if (sub == 0) gcnt[g] = 0;
  __syncthreads();

  for (int t0 = 0; t0 < NN; t0 += TILE) {
    for (int p = t; p < TILE; p += TPB) {
      int j = t0 + p;
      float x = base[3 * j], y = base[3 * j + 1], z = base[3 * j + 2];
      tile[p] = make_float4(x, y, z, __fmul_rn(-0.5f, sqnorm(x, y, z)));
    }
    __syncthreads();
#pragma unroll 8
    for (int c = sub; c < TILE; c += GPP) {
      float4 q = tile[c];
      float s = score_s(q.x, q.y, q.z, q.w, xi, yi, zi);
      if (s >= thr) {
        unsigned long long key = s_key(s, t0 + c);
        unsigned pos = atomicAdd(&gcnt[g], 1u);
        if (pos < (unsigned)CAP) gbuf[g][pos] = key;
      }
    }
    __syncthreads();
  }

  const unsigned cnt = gcnt[g];
  const int gid = b * NN + i;

  if (cnt <= (unsigned)CAP) {
    // ---- sort <=64 keys with 16 lanes (4-deep sorted per lane + pop-merge) ----
    unsigned long long e0 = (sub      < (int)cnt) ? gbuf[g][sub]      : ~0ULL;
    unsigned long long e1 = (sub + 16 < (int)cnt) ? gbuf[g][sub + 16] : ~0ULL;
    unsigned long long e2 = (sub + 32 < (int)cnt) ? gbuf[g][sub + 32] : ~0ULL;
    unsigned long long e3 = (sub + 48 < (int)cnt) ? gbuf[g][sub + 48] : ~0ULL;
    CSWAPU(e0, e1) CSWAPU(e2, e3) CSWAPU(e0, e2) CSWAPU(e1, e3) CSWAPU(e1, e2)
#pragma unroll
    for (int r = 0; r < KK; ++r) {
      unsigned long long m = e0, o;
      o = __shfl_xor(m, 1); m = (o < m) ? o : m;
      o = __shfl_xor(m, 2); m = (o < m) ? o : m;
      o = __shfl_xor(m, 4); m = (o < m) ? o : m;
      o = __shfl_xor(m, 8); m = (o < m) ? o : m;
      if (e0 == m) { e0 = e1; e1 = e2; e2 = e3; e3 = ~0ULL; }  // keys unique -> one lane pops
      if (sub == (r & 15)) idxbuf[gid * KK + r] = (int)(unsigned)(m & 0xFFFFFFFFULL);
    }
  } else {
    // ---- exact fallback (essentially never): per-lane u64 top-10 over global ----
    unsigned long long k0 = ~0ULL, k1 = ~0ULL, k2 = ~0ULL, k3 = ~0ULL, k4 = ~0ULL,
                       k5 = ~0ULL, k6 = ~0ULL, k7 = ~0ULL, k8 = ~0ULL, k9 = ~0ULL;
    for (int c = sub; c < NN; c += GPP) {
      float x = base[3 * c], y = base[3 * c + 1], z = base[3 * c + 2];
      float s = score_s(x, y, z, __fmul_rn(-0.5f, sqnorm(x, y, z)), xi, yi, zi);
      unsigned long long key = s_key(s, c);
      if (key < k9) {
        unsigned long long x2 = key;
        { unsigned long long &x = x2;
          INS2(k0) INS2(k1) INS2(k2) INS2(k3) INS2(k4)
          INS2(k5) INS2(k6) INS2(k7) INS2(k8) INS2(k9) }
      }
    }
#pragma unroll
    for (int r = 0; r < KK; ++r) {
      unsigned long long m = k0, o;
      o = __shfl_xor(m, 1); m = (o < m) ? o : m;
      o = __shfl_xor(m, 2); m = (o < m) ? o : m;
      o = __shfl_xor(m, 4); m = (o < m) ? o : m;
      o = __shfl_xor(m, 8); m = (o < m) ? o : m;
      if (k0 == m) { k0=k1;k1=k2;k2=k3;k3=k4;k4=k5;k5=k6;k6=k7;k7=k8;k8=k9;k9=~0ULL; }
      if (sub == (r & 15)) idxbuf[gid * KK + r] = (int)(unsigned)(m & 0xFFFFFFFFULL);
    }
  }
}

// ---------------- Kernel 2: split-cloud SVD — 1 SVD per thread ----------------
__global__ __launch_bounds__(TPB, 1)
void lfl_svd(const float* __restrict__ xyz1, const float* __restrict__ xyz2,
             const int* __restrict__ idxbuf, double* __restrict__ partials) {
  __shared__ double pv[TPB];
  __shared__ double red1[128], red2[128];
  const int t = threadIdx.x;
  const int half = t >> 7;          // 0: cloud1, 1: cloud2
  const int lt = t & 127;
  const int pid = blockIdx.x * 128 + lt;   // point id 0..NPTS-1
  const int b = pid / NN, i = pid % NN;
  const float* basep = (half == 0) ? (xyz1 + (size_t)b * NN * 3)
                                   : (xyz2 + (size_t)b * NN * 3);
  double p;
  {
    double A[KK][3];
    double cx = 0, cy = 0, cz = 0;
#pragma unroll
    for (int s = 0; s < KK; ++s) {
      int j = idxbuf[pid * KK + s];
      j = ((unsigned)j < (unsigned)NN) ? j : 0;   // defensive: fault -> numeric miss
      A[s][0] = (double)basep[3 * j];
      A[s][1] = (double)basep[3 * j + 1];
      A[s][2] = (double)basep[3 * j + 2];
      cx += A[s][0]; cy += A[s][1]; cz += A[s][2];
    }
    cx *= 0.1; cy *= 0.1; cz *= 0.1;
#pragma unroll
    for (int s = 0; s < KK; ++s) { A[s][0] -= cx; A[s][1] -= cy; A[s][2] -= cz; }
    double nx, ny, nz;
    lapack_normal(A, nx, ny, nz);
    p = ((double)basep[3 * i] - cx) * nx + ((double)basep[3 * i + 1] - cy) * ny +
        ((double)basep[3 * i + 2] - cz) * nz;
  }
  pv[t] = p;
  __syncthreads();

  if (t < 128) {
    double p1 = pv[t], p2 = pv[t + 128];
    double da = fabs(p1) - fabs(p2);
    double df = p2 - p1;
    double bent = df > 0.0 ? df : 0.0;
    red1[t] = da * da;
    red2[t] = bent * bent;
  }
  __syncthreads();
  for (int s = 64; s > 0; s >>= 1) {
    if (t < s) { red1[t] += red1[t + s]; red2[t] += red2[t + s]; }
    __syncthreads();
  }
  if (t == 0) {
    partials[2 * blockIdx.x]     = red1[0];
    partials[2 * blockIdx.x + 1] = red2[0];
  }
}

// ---------------- Kernel 3: parallel deterministic finalize ----------------
__global__ __launch_bounds__(TPB)
void lfl_final(const double* __restrict__ partials, float* __restrict__ out) {
  __shared__ double r1[TPB], r2[TPB];
  const int t = threadIdx.x;
  r1[t] = partials[2 * t];
  r2[t] = partials[2 * t + 1];
  __syncthreads();
  for (int s = TPB / 2; s > 0; s >>= 1) {
    if (t < s) { r1[t] += r1[t + s]; r2[t] += r2[t + s]; }
    __syncthreads();
  }
  if (t == 0) out[0] = (float)((r1[0] + 5.0 * r2[0]) / (double)NPTS);
}

extern "C" void kernel_launch(void* const* d_in, const int* in_sizes, int n_in,
                              void* d_out, int out_size, void* d_ws, size_t ws_size,
                              hipStream_t stream) {
  const float* xyz1 = (const float*)d_in[0];
  const float* xyz2 = (const float*)d_in[1];
  float* out = (float*)d_out;
  double* partials = (double*)d_ws;                      // 4 KB
  int* idxbuf = (int*)((char*)d_ws + 4096);              // 1.31 MB

  lfl_knn<<<KNBLK, TPB, 0, stream>>>(xyz1, idxbuf);
  lfl_svd<<<SVDBLK, TPB, 0, stream>>>(xyz1, xyz2, idxbuf, partials);
  lfl_final<<<1, TPB, 0, stream>>>(partials, out);
}